// Round 11
// baseline (439.577 us; speedup 1.0000x reference)
//
#include <hip/hip_runtime.h>
#include <hip/hip_bf16.h>

// Problem constants
#define B_ 128
#define L_ 105
#define M_ 55
#define D_ 256
#define NCOMBO 18   // 3 patches x 2 branches x 3 layers

// Workspace layout (float offsets)
#define WS_XT    0          // normalized x^T: [B*M][105] = 739200
#define WS_PE    739200     // pos-embed tables: 86*256 = 22016
#define WS_LEFT  761216     // 18 * 27648 (fallback path; MP overlays after mm)
#define WS_RIGHT 1258880    // 18 * 27648 (ACC-B overlays after mm)
#define WS_MM    1756544    // 18 * 11664
#define WS_MP    761216     // 18 * 12544 (over LEFT, after mm)
#define LR_STRIDE 27648
#define MM_STRIDE 11664
#define MP_STRIDE 12544

// ACC split: combos 0-12 at WS_ACC_B (ends 1940480 < WS_LRP); combos 13-17
// in the MP..RIGHT gap at WS_ACC_A (ends 1063424 < WS_RIGHT). Neither span
// overlaps LRP -> zeroing can happen in prep (partial path).
#define WS_ACC_A 987008
#define WS_ACC_B 1258880
#define ZA_F4 19104          // 76416 floats / 4  (combos 13-17)
#define ZB_F4 170400         // 681600 floats / 4 (combos 0-12)
#define Z_TOT_F4 (ZA_F4 + ZB_F4)
#define Z_BLOCKS ((Z_TOT_F4 + 255) / 256)   // 741

// K-split partial region (only used when ws_size is large enough)
#define WS_LRP        1966592
#define LRP_KZ_STRIDE 27648
#define LRP_C_STRIDE  110592
#define LRP_HALF      1990656
#define WS_NEED_BYTES ((size_t)(WS_LRP + 2 * LRP_HALF) * 4)

__constant__ int c_peOff[6] = {0, 35, 38, 59, 64, 79};
// acc float-offset per combo (split layout; see above)
__constant__ int c_accws[18] = {
    1258880, 1415680, 1572480,           // <3,0> l=0..2
    1729280, 1730432, 1731584,           // <3,1>
    1732736, 1789184, 1845632,           // <5,0>
    1902080, 1905280, 1908480,           // <5,1>
    1911680,                             // <7,0> l=0
    987008, 1015808,                     // <7,0> l=1..2 (gap region)
    1044608, 1050880, 1057152};          // <7,1> (gap region)

__device__ __forceinline__ void combo_dims(int c, int& i, int& br, int& l,
                                           int& p, int& n, int& Cin, int& T, int& J) {
    i = c / 6; br = (c % 6) / 3; l = c % 3;
    p = 3 + 2 * i;
    n = L_ / p;
    Cin = br ? n : p;
    T   = br ? p : n;
    J = 3 * Cin;
}

__device__ __forceinline__ void zero_span(float* __restrict__ ws, int idx) {
    float4 z; z.x = 0.f; z.y = 0.f; z.z = 0.f; z.w = 0.f;
    if (idx < ZA_F4) ((float4*)(ws + WS_ACC_A))[idx] = z;
    else if (idx < Z_TOT_F4) ((float4*)(ws + WS_ACC_B))[idx - ZA_F4] = z;
}

// ---------------- prep: RevIN + pos-embed + Mp pad prefill + ACC zero ----------------
#define PREP_REVIN_BLOCKS 3520   // 7040 bm / 2
#define PREP_PE_END   (PREP_REVIN_BLOCKS + 6)
#define PREP_PAD_END  (PREP_PE_END + NCOMBO)
#define PREP_BLOCKS   (PREP_PAD_END + Z_BLOCKS)
__global__ __launch_bounds__(256) void prep_kernel(const float* __restrict__ x,
                                                   float* __restrict__ ws) {
    int bid = blockIdx.x;
    if (bid < PREP_REVIN_BLOCKS) {
        int tid2 = threadIdx.x & 127;
        int half = threadIdx.x >> 7;
        int bm = bid * 2 + half;
        int b = bm / M_, m = bm % M_;
        __shared__ float s1[2][128], s2[2][128];
        float v = 0.f;
        if (tid2 < L_) v = x[(b * L_ + tid2) * M_ + m];
        s1[half][tid2] = v; s2[half][tid2] = v * v;
        __syncthreads();
        for (int off = 64; off > 0; off >>= 1) {
            if (tid2 < off) {
                s1[half][tid2] += s1[half][tid2 + off];
                s2[half][tid2] += s2[half][tid2 + off];
            }
            __syncthreads();
        }
        float mean = s1[half][0] * (1.f / L_);
        float var  = s2[half][0] * (1.f / L_) - mean * mean;
        float rstd = rsqrtf(var + 1e-5f);
        if (tid2 < L_) ws[WS_XT + bm * L_ + tid2] = (v - mean) * rstd;
    } else if (bid < PREP_PE_END) {
        int bi = bid - PREP_REVIN_BLOCKS;          // 0..5
        int i = bi / 2, br = bi % 2;
        int p = 3 + 2 * i, n = L_ / p;
        int T = br ? p : n;
        int d = threadIdx.x;
        float divv = expf(-(float)(d & ~1) * (logf(10000.f) / (float)D_));
        float* base = ws + WS_PE + c_peOff[bi] * D_;
        for (int t = 0; t < T; ++t) {
            float arg = (float)t * divv;
            base[t * D_ + d] = (d & 1) ? cosf(arg) : sinf(arg);
        }
    } else if (bid < PREP_PAD_END) {
        int c = bid - PREP_PE_END;                 // 0..17: Mp pad prefill
        int i, br, l, p, n, Cin, T, J; combo_dims(c, i, br, l, p, n, Cin, T, J);
        int Cinp = (Cin + 3) & ~3;
        int Jp = 3 * Cinp;
        int T4 = (T + 3) & ~3;
        int W = Jp + T4;
        float* Mp = ws + WS_MP + c * MP_STRIDE;
        for (int e = threadIdx.x; e < W * W; e += 256) {
            int r = e / W, o = e % W;
            bool vr   = (r < Jp) ? ((r % Cinp) < Cin) : (r - Jp < T);
            bool brow = (r >= Jp) && (r - Jp < T);
            bool vc   = (o < Jp) ? ((o % Cinp) < Cin) : (o - Jp < T);
            if (!(vr && vc))
                Mp[e] = (brow && o >= Jp && !vc) ? -1e30f : 0.f;
        }
    } else {
        // ACC zero (safe pre-lr2: spans are disjoint from LRP/MP/XT/PE).
        int idx = (bid - PREP_PAD_END) * 256 + threadIdx.x;
        zero_span(ws, idx);
    }
}

// ---------------- lr2: K-split x4, 8-row tiles, unique-writer partials ----------------
__global__ __launch_bounds__(256) void lr2_kernel(
                          const float* __restrict__ w0, const float* __restrict__ w1,
                          const float* __restrict__ w2c, const float* __restrict__ w3,
                          const float* __restrict__ w4, const float* __restrict__ w5,
                          const float* __restrict__ Wq, const float* __restrict__ bq,
                          const float* __restrict__ Wk, const float* __restrict__ bk,
                          float* __restrict__ ws) {
    int c = blockIdx.x;
    int i, br, l, p, n, Cin, T, J; combo_dims(c, i, br, l, p, n, Cin, T, J);
    int Mdim = J + T;
    int r0 = blockIdx.y * 8;
    if (r0 >= Mdim) return;
    int kz = blockIdx.z;
    int d0 = kz * 64;
    int wi = i * 2 + br;
    const float* conv = (wi == 0) ? w0 : (wi == 1) ? w1 : (wi == 2) ? w2c
                       : (wi == 3) ? w3 : (wi == 4) ? w4 : w5;
    __shared__ float S[8][64];
    int tid = threadIdx.x;
    for (int idx = tid; idx < 8 * 64; idx += 256) {
        int rr = idx >> 6, dd = idx & 63;
        int row = r0 + rr; float val = 0.f;
        int d = d0 + dd;
        if (row < J) val = conv[d * J + row];
        else if (row < Mdim) val = ws[WS_PE + (c_peOff[wi] + (row - J)) * D_ + d];
        S[rr][dd] = val;
    }
    __syncthreads();
    const float* wqp = Wq + l * D_ * D_;
    const float* wkp = Wk + l * D_ * D_;
    float accL[8], accR[8];
#pragma unroll
    for (int rr = 0; rr < 8; ++rr) { accL[rr] = 0.f; accR[rr] = 0.f; }
    int o = tid;
#pragma unroll 8
    for (int dd = 0; dd < 64; ++dd) {
        int d = d0 + dd;
        float wqv = wqp[d * D_ + o];
        float wkv = wkp[d * D_ + o];
#pragma unroll
        for (int rr = 0; rr < 8; ++rr) {
            float sv = S[rr][dd];
            accL[rr] += sv * wqv;
            accR[rr] += sv * wkv;
        }
    }
    float bqv = (kz == 0) ? bq[l * D_ + o] : 0.f;
    float bkv = (kz == 0) ? bk[l * D_ + o] : 0.f;
    float* Lp = ws + WS_LRP + c * LRP_C_STRIDE + kz * LRP_KZ_STRIDE;
    float* Rp = Lp + LRP_HALF;
#pragma unroll
    for (int rr = 0; rr < 8; ++rr) {
        int row = r0 + rr;
        if (row < Mdim) {
            float aq = (row >= J) ? bqv : 0.f;
            float ak = (row >= J) ? bkv : 0.f;
            Lp[row * D_ + o] = accL[rr] + aq;
            Rp[row * D_ + o] = accR[rr] + ak;
        }
    }
}

// ---------------- Fallback lr: 4 rows per block, full K ----------------
__global__ __launch_bounds__(256) void lr_kernel(
                          const float* __restrict__ w0, const float* __restrict__ w1,
                          const float* __restrict__ w2c, const float* __restrict__ w3,
                          const float* __restrict__ w4, const float* __restrict__ w5,
                          const float* __restrict__ Wq, const float* __restrict__ bq,
                          const float* __restrict__ Wk, const float* __restrict__ bk,
                          float* __restrict__ ws) {
    int c = blockIdx.x;
    int i, br, l, p, n, Cin, T, J; combo_dims(c, i, br, l, p, n, Cin, T, J);
    int Mdim = J + T;
    int r0 = blockIdx.y * 4;
    if (r0 >= Mdim) return;
    int wi = i * 2 + br;
    const float* conv = (wi == 0) ? w0 : (wi == 1) ? w1 : (wi == 2) ? w2c
                       : (wi == 3) ? w3 : (wi == 4) ? w4 : w5;
    __shared__ float S[4][256];
    int tid = threadIdx.x;
    for (int idx = tid; idx < 4 * 256; idx += 256) {
        int rr = idx >> 8, dd = idx & 255;
        int row = r0 + rr; float val = 0.f;
        if (row < J) val = conv[dd * J + row];
        else if (row < Mdim) val = ws[WS_PE + (c_peOff[wi] + (row - J)) * D_ + dd];
        S[rr][dd] = val;
    }
    __syncthreads();
    const float* wqp = Wq + l * D_ * D_;
    const float* wkp = Wk + l * D_ * D_;
    float accL[4], accR[4];
#pragma unroll
    for (int rr = 0; rr < 4; ++rr) { accL[rr] = 0.f; accR[rr] = 0.f; }
    int o = tid;
#pragma unroll 8
    for (int d = 0; d < D_; ++d) {
        float wqv = wqp[d * D_ + o];
        float wkv = wkp[d * D_ + o];
#pragma unroll
        for (int rr = 0; rr < 4; ++rr) {
            float sv = S[rr][d];
            accL[rr] += sv * wqv;
            accR[rr] += sv * wkv;
        }
    }
    float bqv = bq[l * D_ + o], bkv = bk[l * D_ + o];
#pragma unroll
    for (int rr = 0; rr < 4; ++rr) {
        int row = r0 + rr;
        if (row < Mdim) {
            float aq = (row >= J) ? bqv : 0.f;
            float ak = (row >= J) ? bkv : 0.f;
            ws[WS_LEFT  + c * LR_STRIDE + row * D_ + o] = accL[rr] + aq;
            ws[WS_RIGHT + c * LR_STRIDE + row * D_ + o] = accR[rr] + ak;
        }
    }
}

// ---------------- M' = Left @ Right^T ----------------
// Partial path: scatter-writes DIRECTLY into packed Mp (pads prefilled by
// prep) — the pack dispatch is skipped. Fallback: writes WS_MM as before.
__global__ void mm_kernel(float* __restrict__ ws, int use_partial) {
    int c = blockIdx.x;
    int i, br, l, p, n, Cin, T, J; combo_dims(c, i, br, l, p, n, Cin, T, J);
    int Mdim = J + T;
    int tr = blockIdx.y / 7, tc = blockIdx.y % 7;
    int r0 = tr * 16, c0 = tc * 16;
    if (r0 >= Mdim || c0 >= Mdim) return;
    __shared__ __align__(16) float Lb[16][260], Rb[16][260];
    int tid = threadIdx.x;
    if (use_partial) {
        const float* Lp = ws + WS_LRP + c * LRP_C_STRIDE;
        const float* Rp = Lp + LRP_HALF;
        for (int idx = tid; idx < 16 * 256; idx += 256) {
            int rr = idx >> 8, d = idx & 255;
            int rL = r0 + rr, rR = c0 + rr;
            float lv = 0.f, rv = 0.f;
            if (rL < Mdim) {
                int base = rL * D_ + d;
                lv = Lp[base] + Lp[base + LRP_KZ_STRIDE]
                   + Lp[base + 2 * LRP_KZ_STRIDE] + Lp[base + 3 * LRP_KZ_STRIDE];
            }
            if (rR < Mdim) {
                int base = rR * D_ + d;
                rv = Rp[base] + Rp[base + LRP_KZ_STRIDE]
                   + Rp[base + 2 * LRP_KZ_STRIDE] + Rp[base + 3 * LRP_KZ_STRIDE];
            }
            Lb[rr][d] = lv; Rb[rr][d] = rv;
        }
    } else {
        for (int idx = tid; idx < 16 * 256; idx += 256) {
            int rr = idx >> 8, d = idx & 255;
            int rL = r0 + rr, rR = c0 + rr;
            Lb[rr][d] = (rL < Mdim) ? ws[WS_LEFT  + c * LR_STRIDE + rL * D_ + d] : 0.f;
            Rb[rr][d] = (rR < Mdim) ? ws[WS_RIGHT + c * LR_STRIDE + rR * D_ + d] : 0.f;
        }
    }
    __syncthreads();
    int rr = tid / 16, cc = tid % 16;
    const float4* lrow = (const float4*)(&Lb[rr][0]);
    const float4* rrow = (const float4*)(&Rb[cc][0]);
    float acc = 0.f;
#pragma unroll 8
    for (int d4 = 0; d4 < 64; ++d4) {
        float4 a = lrow[d4], bb = rrow[d4];
        acc += a.x * bb.x + a.y * bb.y + a.z * bb.z + a.w * bb.w;
    }
    int r = r0 + rr, cth = c0 + cc;
    if (r < Mdim && cth < Mdim) {
        if (use_partial) {
            int Cinp = (Cin + 3) & ~3;
            int Jp = 3 * Cinp;
            int W = Jp + ((T + 3) & ~3);
            int rp = (r   < J) ? ((r   % 3) * Cinp + r   / 3) : (Jp + r   - J);
            int op = (cth < J) ? ((cth % 3) * Cinp + cth / 3) : (Jp + cth - J);
            ws[WS_MP + c * MP_STRIDE + rp * W + op] = acc;
        } else {
            ws[WS_MM + c * MM_STRIDE + r * Mdim + cth] = acc;
        }
    }
}

// ---------------- Pack M' into reordered/padded Mp (FALLBACK path only) ----------------
__global__ void pack_kernel(float* __restrict__ ws) {
    int c = blockIdx.x;
    int i, br, l, p, n, Cin, T, J; combo_dims(c, i, br, l, p, n, Cin, T, J);
    int Mdim = J + T;
    int Cinp = (Cin + 3) & ~3;
    int Jp = 3 * Cinp;
    int T4 = (T + 3) & ~3;
    int W = Jp + T4;
    const float* MMc = ws + WS_MM + c * MM_STRIDE;
    float* Mp = ws + WS_MP + c * MP_STRIDE;
    for (int e = blockIdx.y * 256 + threadIdx.x; e < W * W; e += 16 * 256) {
        int r = e / W, o = e % W;
        int srcr = -1, srcc = -1;
        bool brow = false;
        if (r < Jp) {
            int k = r / Cinp, cin = r % Cinp;
            if (cin < Cin) srcr = cin * 3 + k;
        } else {
            int t = r - Jp;
            if (t < T) { srcr = J + t; brow = true; }
        }
        if (o < Jp) {
            int k2 = o / Cinp, cin2 = o % Cinp;
            if (cin2 < Cin) srcc = cin2 * 3 + k2;
        } else {
            int s = o - Jp;
            if (s < T) srcc = J + s;
        }
        float val;
        if (srcr >= 0 && srcc >= 0) val = MMc[srcr * Mdim + srcc];
        else if (brow && o >= Jp && srcc < 0) val = -1e30f;  // padded-s bias: kill in softmax
        else val = 0.f;
        Mp[e] = val;
    }
}

// ---------------- Zero ACC spans (FALLBACK path only; after pack) ----------------
__global__ void zero_acc(float* __restrict__ ws) {
    zero_span(ws, blockIdx.x * 256 + threadIdx.x);
}

// ---------------- Fused attention ----------
// R11 = R10's attn2 + TH=2 for <7,0> (NT 300->160: removes the 44-thread
// TPB=2 second pass every barrier waited on; LDS 37.4KB->21.5KB -> 7
// blocks/CU from 4) + split ACC addressing (c_accws).
template<int P, int BR>
__global__ __launch_bounds__(256) void attn2(const float* __restrict__ ws,
                                             float* __restrict__ wsw) {
    constexpr int N    = L_ / P;
    constexpr int Cin  = BR ? N : P;
    constexpr int T    = BR ? P : N;
    constexpr int Cinp = (Cin + 3) & ~3;
    constexpr int Jp   = 3 * Cinp;
    constexpr int JP4  = Jp / 4;
    constexpr int T4   = (T + 3) & ~3;
    constexpr int W    = Jp + T4;
    constexpr int W4   = W / 4;
    constexpr int ST   = T4 + 1;
    constexpr int II   = (P - 3) / 2;
    constexpr int MC   = BR ? (P == 3 ? 12 : 8) : (P == 7 ? 8 : 4);
    constexpr int TH   = (BR == 0 && P != 5) ? 2 : 1;     // t-split: <3,0> and <7,0>
    constexpr int TSUB = (T + TH - 1) / TH;               // rows per t-half
    constexpr int GR   = MC * TSUB + 1;                   // G float4-rows (odd)
    constexpr int NT   = (MC / 4) * TSUB * W4;
    constexpr int TPB  = (NT + 255) / 256;
    constexpr int MCQ  = MC / 4;
    constexpr int CQ   = Cinp / 4;
    constexpr int CQP  = CQ | 1;                  // padded X2A row stride (float4s, odd)
    constexpr int S4N  = T4 / 4;
    constexpr int XTR4 = Cinp * MCQ + 1;          // padded X2T row stride (float4s, odd)

    // LDS layout: [X2A][G^T][X2T][MSL(BR==0)]; S overlays X2T(+MSL) after G-phase
    constexpr int OFF_X2A = 0;
    constexpr int SZ_X2A  = MC * T * CQP * 4;
    constexpr int OFF_G   = OFF_X2A + SZ_X2A;
    constexpr int SZ_G    = 4 * W4 * GR;          // transposed: [W4][GR] float4s
    constexpr int OFF_X2T = OFF_G + SZ_G;
    constexpr int SZ_X2T  = T * XTR4 * 4;
    constexpr int OFF_MSL = OFF_X2T + SZ_X2T;
    constexpr int SZ_MSL  = BR ? 0 : Cinp * W;
    constexpr int OFF_S   = OFF_X2T;              // X2T (+MSL) dead after G-phase
    constexpr int SZ_S    = MC * TSUB * ST;
    constexpr int END_A   = OFF_MSL + SZ_MSL;
    constexpr int END_B   = OFF_S + SZ_S;
    constexpr int TOT     = (END_A > END_B) ? END_A : END_B;
    static_assert(TOT * 4 <= 65536, "LDS budget");

    __shared__ __align__(16) float smem[TOT];
    const int tid = threadIdx.x;
    const int b = blockIdx.x, l = blockIdx.y;
    const int sp = blockIdx.z / TH;
    const int th = blockIdx.z % TH;
    const int t0 = th * TSUB;
    const int TC = (T - t0 < TSUB) ? (T - t0) : TSUB;     // valid t rows this block
    const int c = II * 6 + BR * 3 + l;
    const int m0 = sp * MC;
    const int vm = (M_ - m0 < MC) ? (M_ - m0) : MC;

    const float*  Mpg  = ws + WS_MP + c * MP_STRIDE;
    const float4* Mpg4 = (const float4*)Mpg;

    // ---- stage X2A: [mc][trow][cin..pad], per-trow stride CQP float4 ----
    for (int e = tid; e < MC * T * CQP * 4; e += 256) {
        int cin  = e % (CQP * 4);
        int trow = (e / (CQP * 4)) % T;
        int mcol = e / (CQP * 4 * T);
        float v = 0.f;
        if (cin < Cin && m0 + mcol < M_)
            v = ws[WS_XT + (size_t)(b * M_ + m0 + mcol) * L_ + trow * Cin + cin];
        smem[OFF_X2A + e] = v;
    }
    // ---- stage X2T: [trow]([cin][mcol] + pad), per-trow stride XTR4 float4 ----
    for (int e = tid; e < T * XTR4 * 4; e += 256) {
        int w    = e % (XTR4 * 4);
        int trow = e / (XTR4 * 4);
        float v = 0.f;
        if (w < Cinp * MC) {
            int mcol = w % MC, cin = w / MC;
            if (cin < Cin && m0 + mcol < M_)
                v = ws[WS_XT + (size_t)(b * M_ + m0 + mcol) * L_ + trow * Cin + cin];
        }
        smem[OFF_X2T + e] = v;
    }
    __syncthreads();

    const float4* X2T4 = (const float4*)(smem + OFF_X2T);
    const float4* X2A4 = (const float4*)(smem + OFF_X2A);
    float4*       MSL4 = (float4*)(smem + OFF_MSL);
    float4*       G4w  = (float4*)(smem + OFF_G);
    const float4* G4   = (const float4*)(smem + OFF_G);

    // ---- G-phase: register-tiled GEMM over this block's t rows ----
    float a[TPB][4][4];
#pragma unroll
    for (int tt = 0; tt < TPB; ++tt) {
        int q = tid + tt * 256;
        if (q < NT) {
            int o4 = q % W4, tl = (q / W4) % TSUB;
            if (tl < TC) {
                float4 bv = Mpg4[(Jp + t0 + tl) * W4 + o4];
#pragma unroll
                for (int am = 0; am < 4; ++am) {
                    a[tt][am][0] = bv.x; a[tt][am][1] = bv.y;
                    a[tt][am][2] = bv.z; a[tt][am][3] = bv.w;
                }
            }
        }
    }
    if constexpr (BR == 0) {
        // MSL LDS staging per k (tiny: Cinp*W4 <= 96 float4s)
        for (int k = 0; k < 3; ++k) {
            for (int e = tid; e < Cinp * W4; e += 256)
                MSL4[e] = Mpg4[k * Cinp * W4 + e];
            __syncthreads();
#pragma unroll
            for (int tt = 0; tt < TPB; ++tt) {
                int q = tid + tt * 256;
                if (q < NT) {
                    int o4 = q % W4, tl = (q / W4) % TSUB, m4 = q / (W4 * TSUB);
                    if (tl < TC) {
                        int trow = t0 + tl + k - 1;
                        if (trow < 0) trow += T;
                        if (trow >= T) trow -= T;
                        const float4* xp = X2T4 + trow * XTR4 + m4;
                        const float4* mp = MSL4 + o4;
#pragma unroll 4
                        for (int cin = 0; cin < Cinp; ++cin) {
                            float4 x4 = xp[cin * MCQ];
                            float4 mv = mp[cin * W4];
#pragma unroll
                            for (int aq = 0; aq < 4; ++aq) {
                                float m = (aq == 0) ? mv.x : (aq == 1) ? mv.y
                                        : (aq == 2) ? mv.z : mv.w;
                                a[tt][0][aq] += x4.x * m;
                                a[tt][1][aq] += x4.y * m;
                                a[tt][2][aq] += x4.z * m;
                                a[tt][3][aq] += x4.w * m;
                            }
                        }
                    }
                }
            }
            __syncthreads();
        }
    } else {
        __syncthreads();
#pragma unroll
        for (int k = 0; k < 3; ++k) {
#pragma unroll
            for (int tt = 0; tt < TPB; ++tt) {
                int q = tid + tt * 256;
                if (q < NT) {
                    int o4 = q % W4, tl = (q / W4) % TSUB, m4 = q / (W4 * TSUB);
                    if (tl < TC) {
                        int trow = t0 + tl + k - 1;
                        if (trow < 0) trow += T;
                        if (trow >= T) trow -= T;
                        const float4* xp = X2T4 + trow * XTR4 + m4;
                        const float4* mp = Mpg4 + k * Cinp * W4 + o4;   // GLOBAL (L2)
#pragma unroll 4
                        for (int cin = 0; cin < Cinp; ++cin) {
                            float4 x4 = xp[cin * MCQ];
                            float4 mv = mp[cin * W4];
#pragma unroll
                            for (int aq = 0; aq < 4; ++aq) {
                                float m = (aq == 0) ? mv.x : (aq == 1) ? mv.y
                                        : (aq == 2) ? mv.z : mv.w;
                                a[tt][0][aq] += x4.x * m;
                                a[tt][1][aq] += x4.y * m;
                                a[tt][2][aq] += x4.z * m;
                                a[tt][3][aq] += x4.w * m;
                            }
                        }
                    }
                }
            }
        }
    }
#pragma unroll
    for (int tt = 0; tt < TPB; ++tt) {
        int q = tid + tt * 256;
        if (q < NT) {
            int o4 = q % W4, tl = (q / W4) % TSUB, m4 = q / (W4 * TSUB);
            if (tl < TC) {
#pragma unroll
                for (int am = 0; am < 4; ++am) {
                    float4 o;
                    o.x = a[tt][am][0]; o.y = a[tt][am][1];
                    o.z = a[tt][am][2]; o.w = a[tt][am][3];
                    G4w[o4 * GR + (m4 * 4 + am) * TSUB + tl] = o;   // transposed
                }
            }
        }
    }
    __syncthreads();

    // ---- S-phase: tl-fastest lanes; register halo over the 6 X2A rows ----
    for (int it = tid; it < MC * TSUB * S4N; it += 256) {
        int tl = it % TSUB;
        int s4 = (it / TSUB) % S4N;
        int mc = it / (TSUB * S4N);
        if (tl >= TC) continue;
        int mrow = mc * TSUB + tl;
        float4 bi = G4[(JP4 + s4) * GR + mrow];                     // transposed
        float acc[4] = {bi.x, bi.y, bi.z, bi.w};
#pragma unroll 2
        for (int cinq = 0; cinq < CQ; ++cinq) {
            float4 xr[6];
#pragma unroll
            for (int kk = 0; kk < 6; ++kk) {
                int r = s4 * 4 - 1 + kk;
                if (r < 0) r += T;
                if (r >= T) r -= T;
                xr[kk] = X2A4[(mc * T + r) * CQP + cinq];
            }
#pragma unroll
            for (int k = 0; k < 3; ++k) {
                float4 g = G4[(k * CQ + cinq) * GR + mrow];         // transposed
#pragma unroll
                for (int q = 0; q < 4; ++q) {
                    float4 x4 = xr[q + k];
                    acc[q] += g.x * x4.x + g.y * x4.y + g.z * x4.z + g.w * x4.w;
                }
            }
        }
#pragma unroll
        for (int q = 0; q < 4; ++q)
            smem[OFF_S + (mc * TSUB + tl) * ST + s4 * 4 + q] = 0.0625f * acc[q];
    }
    __syncthreads();

    // ---- register single-pass softmax (reads T4, writes T; pads exp->0) ----
    for (int rid = tid; rid < MC * TSUB; rid += 256) {
        int mc = rid / TSUB, tl = rid % TSUB;
        if (tl >= TC) continue;
        int base = OFF_S + (mc * TSUB + tl) * ST;
        float pr[T4];
#pragma unroll
        for (int s = 0; s < T4; ++s) pr[s] = smem[base + s];
        float mx = -1e30f;
#pragma unroll
        for (int s = 0; s < T4; ++s) mx = fmaxf(mx, pr[s]);
        float sum = 0.f;
#pragma unroll
        for (int s = 0; s < T4; ++s) { pr[s] = __expf(pr[s] - mx); sum += pr[s]; }
        float inv = 1.f / sum;
#pragma unroll
        for (int s = 0; s < T; ++s) smem[base + s] = pr[s] * inv;
    }
    __syncthreads();

    float* accp = wsw + c_accws[c] + b * T * T;
    for (int e = tid; e < TC * T; e += 256) {
        int tl = e / T, s = e % T;
        float v = 0.f;
        for (int mc = 0; mc < vm; ++mc)
            v += smem[OFF_S + (mc * TSUB + tl) * ST + s];
        atomicAdd(&accp[(t0 + tl) * T + s], v);
    }
}

// ---------------- Expand accumulated means to the full output ----------------
template<int P, int BR>
__device__ __forceinline__ void expand_body(const float* __restrict__ acc,
                                            float* __restrict__ outp) {
    constexpr int T = BR ? P : (L_ / P);
    for (int idx = threadIdx.x; idx < L_ * L_; idx += 256) {
        int r = idx / L_, c2 = idx % L_;
        int rt = BR ? (r % P) : (r / P);
        int ct = BR ? (c2 % P) : (c2 / P);
        outp[idx] = acc[rt * T + ct];
    }
}

__global__ __launch_bounds__(256) void expand_kernel(const float* __restrict__ ws,
                                                     float* __restrict__ out) {
    int c = blockIdx.x, b = blockIdx.y;
    int i = c / 6, br = (c % 6) / 3, l = c % 3;
    int p = 3 + 2 * i;
    int T = br ? p : (L_ / p);
    __shared__ float sAcc[1232];
    int abase = c_accws[c] + b * T * T;
    for (int idx = threadIdx.x; idx < T * T; idx += 256)
        sAcc[idx] = ws[abase + idx] * (1.f / (float)M_);
    __syncthreads();
    float* outp = out + ((size_t)(br * 9 + i * 3 + l) * B_ + (size_t)b) * (size_t)(L_ * L_);
    int key = i * 2 + br;
    switch (key) {
        case 0: expand_body<3, 0>(sAcc, outp); break;
        case 1: expand_body<3, 1>(sAcc, outp); break;
        case 2: expand_body<5, 0>(sAcc, outp); break;
        case 3: expand_body<5, 1>(sAcc, outp); break;
        case 4: expand_body<7, 0>(sAcc, outp); break;
        case 5: expand_body<7, 1>(sAcc, outp); break;
    }
}

extern "C" void kernel_launch(void* const* d_in, const int* in_sizes, int n_in,
                              void* d_out, int out_size, void* d_ws, size_t ws_size,
                              hipStream_t stream) {
    const float* x   = (const float*)d_in[0];
    const float* cp0 = (const float*)d_in[1];
    const float* cn0 = (const float*)d_in[2];
    const float* cp1 = (const float*)d_in[3];
    const float* cn1 = (const float*)d_in[4];
    const float* cp2 = (const float*)d_in[5];
    const float* cn2 = (const float*)d_in[6];
    const float* Wq  = (const float*)d_in[7];
    const float* bq  = (const float*)d_in[8];
    const float* Wk  = (const float*)d_in[9];
    const float* bk  = (const float*)d_in[10];
    float* ws = (float*)d_ws;
    float* out = (float*)d_out;

    const int use_partial = (ws_size >= WS_NEED_BYTES) ? 1 : 0;

    hipLaunchKernelGGL(prep_kernel, dim3(PREP_BLOCKS), dim3(256), 0, stream, x, ws);
    if (use_partial) {
        hipLaunchKernelGGL(lr2_kernel, dim3(NCOMBO, 14, 4), dim3(256), 0, stream,
                           cp0, cn0, cp1, cn1, cp2, cn2, Wq, bq, Wk, bk, ws);
    } else {
        hipLaunchKernelGGL(lr_kernel, dim3(NCOMBO, 27), dim3(256), 0, stream,
                           cp0, cn0, cp1, cn1, cp2, cn2, Wq, bq, Wk, bk, ws);
    }
    hipLaunchKernelGGL(mm_kernel, dim3(NCOMBO, 49), dim3(256), 0, stream, ws, use_partial);
    if (!use_partial) {
        // fallback: mm wrote WS_MM; reorder into Mp, then zero ACC spans
        // (they overlay RIGHT/MM which lr/mm used after prep's zeroing).
        hipLaunchKernelGGL(pack_kernel, dim3(NCOMBO, 16), dim3(256), 0, stream, ws);
        hipLaunchKernelGGL(zero_acc, dim3(Z_BLOCKS), dim3(256), 0, stream, ws);
    }

    // z = m-splits x t-halves (TH=2 for <3,0> and <7,0>)
    hipLaunchKernelGGL((attn2<3, 0>), dim3(B_, 3, 28), dim3(256), 0, stream, ws, ws); // MC=4,TH=2
    hipLaunchKernelGGL((attn2<3, 1>), dim3(B_, 3, 5),  dim3(256), 0, stream, ws, ws); // MC=12
    hipLaunchKernelGGL((attn2<5, 0>), dim3(B_, 3, 14), dim3(256), 0, stream, ws, ws); // MC=4
    hipLaunchKernelGGL((attn2<5, 1>), dim3(B_, 3, 7),  dim3(256), 0, stream, ws, ws); // MC=8
    hipLaunchKernelGGL((attn2<7, 0>), dim3(B_, 3, 14), dim3(256), 0, stream, ws, ws); // MC=8,TH=2
    hipLaunchKernelGGL((attn2<7, 1>), dim3(B_, 3, 7),  dim3(256), 0, stream, ws, ws); // MC=8

    hipLaunchKernelGGL(expand_kernel, dim3(NCOMBO, B_), dim3(256), 0, stream, ws, out);
}

// Round 12
// 432.103 us; speedup vs baseline: 1.0173x; 1.0173x over previous
//
#include <hip/hip_runtime.h>
#include <hip/hip_bf16.h>

// Problem constants
#define B_ 128
#define L_ 105
#define M_ 55
#define D_ 256
#define NCOMBO 18   // 3 patches x 2 branches x 3 layers

// Workspace layout (float offsets)
#define WS_XT    0          // normalized x^T: [B*M][105] = 739200
#define WS_PE    739200     // pos-embed tables: 86*256 = 22016
#define WS_LEFT  761216     // 18 * 27648 (fallback path; MP overlays after mm)
#define WS_RIGHT 1258880    // 18 * 27648 (ACC-B overlays after mm)
#define WS_MM    1756544    // 18 * 11664
#define WS_MP    761216     // 18 * 12544 (over LEFT, after mm)
#define LR_STRIDE 27648
#define MM_STRIDE 11664
#define MP_STRIDE 12544

// ACC split: combos 0-12 at WS_ACC_B (ends 1940480 < WS_LRP); combos 13-17
// in the MP..RIGHT gap at WS_ACC_A (ends 1063424 < WS_RIGHT). Neither span
// overlaps LRP -> zeroing can happen in prep (partial path).
#define WS_ACC_A 987008
#define WS_ACC_B 1258880
#define ZA_F4 19104          // 76416 floats / 4  (combos 13-17)
#define ZB_F4 170400         // 681600 floats / 4 (combos 0-12)
#define Z_TOT_F4 (ZA_F4 + ZB_F4)
#define Z_BLOCKS ((Z_TOT_F4 + 255) / 256)   // 741

// K-split partial region (only used when ws_size is large enough)
#define WS_LRP        1966592
#define LRP_KZ_STRIDE 27648
#define LRP_C_STRIDE  110592
#define LRP_HALF      1990656
#define WS_NEED_BYTES ((size_t)(WS_LRP + 2 * LRP_HALF) * 4)

__constant__ int c_peOff[6] = {0, 35, 38, 59, 64, 79};
// acc float-offset per combo (split layout; see above)
__constant__ int c_accws[18] = {
    1258880, 1415680, 1572480,           // <3,0> l=0..2
    1729280, 1730432, 1731584,           // <3,1>
    1732736, 1789184, 1845632,           // <5,0>
    1902080, 1905280, 1908480,           // <5,1>
    1911680,                             // <7,0> l=0
    987008, 1015808,                     // <7,0> l=1..2 (gap region)
    1044608, 1050880, 1057152};          // <7,1> (gap region)

__device__ __forceinline__ void combo_dims(int c, int& i, int& br, int& l,
                                           int& p, int& n, int& Cin, int& T, int& J) {
    i = c / 6; br = (c % 6) / 3; l = c % 3;
    p = 3 + 2 * i;
    n = L_ / p;
    Cin = br ? n : p;
    T   = br ? p : n;
    J = 3 * Cin;
}

__device__ __forceinline__ void zero_span(float* __restrict__ ws, int idx) {
    float4 z; z.x = 0.f; z.y = 0.f; z.z = 0.f; z.w = 0.f;
    if (idx < ZA_F4) ((float4*)(ws + WS_ACC_A))[idx] = z;
    else if (idx < Z_TOT_F4) ((float4*)(ws + WS_ACC_B))[idx - ZA_F4] = z;
}

// ---------------- prep: RevIN + pos-embed + Mp pad prefill + ACC zero ----------------
#define PREP_REVIN_BLOCKS 3520   // 7040 bm / 2
#define PREP_PE_END   (PREP_REVIN_BLOCKS + 6)
#define PREP_PAD_END  (PREP_PE_END + NCOMBO)
#define PREP_BLOCKS   (PREP_PAD_END + Z_BLOCKS)
__global__ __launch_bounds__(256) void prep_kernel(const float* __restrict__ x,
                                                   float* __restrict__ ws) {
    int bid = blockIdx.x;
    if (bid < PREP_REVIN_BLOCKS) {
        int tid2 = threadIdx.x & 127;
        int half = threadIdx.x >> 7;
        int bm = bid * 2 + half;
        int b = bm / M_, m = bm % M_;
        __shared__ float s1[2][128], s2[2][128];
        float v = 0.f;
        if (tid2 < L_) v = x[(b * L_ + tid2) * M_ + m];
        s1[half][tid2] = v; s2[half][tid2] = v * v;
        __syncthreads();
        for (int off = 64; off > 0; off >>= 1) {
            if (tid2 < off) {
                s1[half][tid2] += s1[half][tid2 + off];
                s2[half][tid2] += s2[half][tid2 + off];
            }
            __syncthreads();
        }
        float mean = s1[half][0] * (1.f / L_);
        float var  = s2[half][0] * (1.f / L_) - mean * mean;
        float rstd = rsqrtf(var + 1e-5f);
        if (tid2 < L_) ws[WS_XT + bm * L_ + tid2] = (v - mean) * rstd;
    } else if (bid < PREP_PE_END) {
        int bi = bid - PREP_REVIN_BLOCKS;          // 0..5
        int i = bi / 2, br = bi % 2;
        int p = 3 + 2 * i, n = L_ / p;
        int T = br ? p : n;
        int d = threadIdx.x;
        float divv = expf(-(float)(d & ~1) * (logf(10000.f) / (float)D_));
        float* base = ws + WS_PE + c_peOff[bi] * D_;
        for (int t = 0; t < T; ++t) {
            float arg = (float)t * divv;
            base[t * D_ + d] = (d & 1) ? cosf(arg) : sinf(arg);
        }
    } else if (bid < PREP_PAD_END) {
        int c = bid - PREP_PE_END;                 // 0..17: Mp pad prefill
        int i, br, l, p, n, Cin, T, J; combo_dims(c, i, br, l, p, n, Cin, T, J);
        int Cinp = (Cin + 3) & ~3;
        int Jp = 3 * Cinp;
        int T4 = (T + 3) & ~3;
        int W = Jp + T4;
        float* Mp = ws + WS_MP + c * MP_STRIDE;
        for (int e = threadIdx.x; e < W * W; e += 256) {
            int r = e / W, o = e % W;
            bool vr   = (r < Jp) ? ((r % Cinp) < Cin) : (r - Jp < T);
            bool brow = (r >= Jp) && (r - Jp < T);
            bool vc   = (o < Jp) ? ((o % Cinp) < Cin) : (o - Jp < T);
            if (!(vr && vc))
                Mp[e] = (brow && o >= Jp && !vc) ? -1e30f : 0.f;
        }
    } else {
        // ACC zero (safe pre-lr2: spans are disjoint from LRP/MP/XT/PE).
        int idx = (bid - PREP_PAD_END) * 256 + threadIdx.x;
        zero_span(ws, idx);
    }
}

// ---------------- lr2: K-split x4, 8-row tiles, unique-writer partials ----------------
__global__ __launch_bounds__(256) void lr2_kernel(
                          const float* __restrict__ w0, const float* __restrict__ w1,
                          const float* __restrict__ w2c, const float* __restrict__ w3,
                          const float* __restrict__ w4, const float* __restrict__ w5,
                          const float* __restrict__ Wq, const float* __restrict__ bq,
                          const float* __restrict__ Wk, const float* __restrict__ bk,
                          float* __restrict__ ws) {
    int c = blockIdx.x;
    int i, br, l, p, n, Cin, T, J; combo_dims(c, i, br, l, p, n, Cin, T, J);
    int Mdim = J + T;
    int r0 = blockIdx.y * 8;
    if (r0 >= Mdim) return;
    int kz = blockIdx.z;
    int d0 = kz * 64;
    int wi = i * 2 + br;
    const float* conv = (wi == 0) ? w0 : (wi == 1) ? w1 : (wi == 2) ? w2c
                       : (wi == 3) ? w3 : (wi == 4) ? w4 : w5;
    __shared__ float S[8][64];
    int tid = threadIdx.x;
    for (int idx = tid; idx < 8 * 64; idx += 256) {
        int rr = idx >> 6, dd = idx & 63;
        int row = r0 + rr; float val = 0.f;
        int d = d0 + dd;
        if (row < J) val = conv[d * J + row];
        else if (row < Mdim) val = ws[WS_PE + (c_peOff[wi] + (row - J)) * D_ + d];
        S[rr][dd] = val;
    }
    __syncthreads();
    const float* wqp = Wq + l * D_ * D_;
    const float* wkp = Wk + l * D_ * D_;
    float accL[8], accR[8];
#pragma unroll
    for (int rr = 0; rr < 8; ++rr) { accL[rr] = 0.f; accR[rr] = 0.f; }
    int o = tid;
#pragma unroll 8
    for (int dd = 0; dd < 64; ++dd) {
        int d = d0 + dd;
        float wqv = wqp[d * D_ + o];
        float wkv = wkp[d * D_ + o];
#pragma unroll
        for (int rr = 0; rr < 8; ++rr) {
            float sv = S[rr][dd];
            accL[rr] += sv * wqv;
            accR[rr] += sv * wkv;
        }
    }
    float bqv = (kz == 0) ? bq[l * D_ + o] : 0.f;
    float bkv = (kz == 0) ? bk[l * D_ + o] : 0.f;
    float* Lp = ws + WS_LRP + c * LRP_C_STRIDE + kz * LRP_KZ_STRIDE;
    float* Rp = Lp + LRP_HALF;
#pragma unroll
    for (int rr = 0; rr < 8; ++rr) {
        int row = r0 + rr;
        if (row < Mdim) {
            float aq = (row >= J) ? bqv : 0.f;
            float ak = (row >= J) ? bkv : 0.f;
            Lp[row * D_ + o] = accL[rr] + aq;
            Rp[row * D_ + o] = accR[rr] + ak;
        }
    }
}

// ---------------- Fallback lr: 4 rows per block, full K ----------------
__global__ __launch_bounds__(256) void lr_kernel(
                          const float* __restrict__ w0, const float* __restrict__ w1,
                          const float* __restrict__ w2c, const float* __restrict__ w3,
                          const float* __restrict__ w4, const float* __restrict__ w5,
                          const float* __restrict__ Wq, const float* __restrict__ bq,
                          const float* __restrict__ Wk, const float* __restrict__ bk,
                          float* __restrict__ ws) {
    int c = blockIdx.x;
    int i, br, l, p, n, Cin, T, J; combo_dims(c, i, br, l, p, n, Cin, T, J);
    int Mdim = J + T;
    int r0 = blockIdx.y * 4;
    if (r0 >= Mdim) return;
    int wi = i * 2 + br;
    const float* conv = (wi == 0) ? w0 : (wi == 1) ? w1 : (wi == 2) ? w2c
                       : (wi == 3) ? w3 : (wi == 4) ? w4 : w5;
    __shared__ float S[4][256];
    int tid = threadIdx.x;
    for (int idx = tid; idx < 4 * 256; idx += 256) {
        int rr = idx >> 8, dd = idx & 255;
        int row = r0 + rr; float val = 0.f;
        if (row < J) val = conv[dd * J + row];
        else if (row < Mdim) val = ws[WS_PE + (c_peOff[wi] + (row - J)) * D_ + dd];
        S[rr][dd] = val;
    }
    __syncthreads();
    const float* wqp = Wq + l * D_ * D_;
    const float* wkp = Wk + l * D_ * D_;
    float accL[4], accR[4];
#pragma unroll
    for (int rr = 0; rr < 4; ++rr) { accL[rr] = 0.f; accR[rr] = 0.f; }
    int o = tid;
#pragma unroll 8
    for (int d = 0; d < D_; ++d) {
        float wqv = wqp[d * D_ + o];
        float wkv = wkp[d * D_ + o];
#pragma unroll
        for (int rr = 0; rr < 4; ++rr) {
            float sv = S[rr][d];
            accL[rr] += sv * wqv;
            accR[rr] += sv * wkv;
        }
    }
    float bqv = bq[l * D_ + o], bkv = bk[l * D_ + o];
#pragma unroll
    for (int rr = 0; rr < 4; ++rr) {
        int row = r0 + rr;
        if (row < Mdim) {
            float aq = (row >= J) ? bqv : 0.f;
            float ak = (row >= J) ? bkv : 0.f;
            ws[WS_LEFT  + c * LR_STRIDE + row * D_ + o] = accL[rr] + aq;
            ws[WS_RIGHT + c * LR_STRIDE + row * D_ + o] = accR[rr] + ak;
        }
    }
}

// ---------------- M' = Left @ Right^T ----------------
// Partial path: scatter-writes DIRECTLY into packed Mp (pads prefilled by
// prep) — the pack dispatch is skipped. Fallback: writes WS_MM as before.
__global__ void mm_kernel(float* __restrict__ ws, int use_partial) {
    int c = blockIdx.x;
    int i, br, l, p, n, Cin, T, J; combo_dims(c, i, br, l, p, n, Cin, T, J);
    int Mdim = J + T;
    int tr = blockIdx.y / 7, tc = blockIdx.y % 7;
    int r0 = tr * 16, c0 = tc * 16;
    if (r0 >= Mdim || c0 >= Mdim) return;
    __shared__ __align__(16) float Lb[16][260], Rb[16][260];
    int tid = threadIdx.x;
    if (use_partial) {
        const float* Lp = ws + WS_LRP + c * LRP_C_STRIDE;
        const float* Rp = Lp + LRP_HALF;
        for (int idx = tid; idx < 16 * 256; idx += 256) {
            int rr = idx >> 8, d = idx & 255;
            int rL = r0 + rr, rR = c0 + rr;
            float lv = 0.f, rv = 0.f;
            if (rL < Mdim) {
                int base = rL * D_ + d;
                lv = Lp[base] + Lp[base + LRP_KZ_STRIDE]
                   + Lp[base + 2 * LRP_KZ_STRIDE] + Lp[base + 3 * LRP_KZ_STRIDE];
            }
            if (rR < Mdim) {
                int base = rR * D_ + d;
                rv = Rp[base] + Rp[base + LRP_KZ_STRIDE]
                   + Rp[base + 2 * LRP_KZ_STRIDE] + Rp[base + 3 * LRP_KZ_STRIDE];
            }
            Lb[rr][d] = lv; Rb[rr][d] = rv;
        }
    } else {
        for (int idx = tid; idx < 16 * 256; idx += 256) {
            int rr = idx >> 8, d = idx & 255;
            int rL = r0 + rr, rR = c0 + rr;
            Lb[rr][d] = (rL < Mdim) ? ws[WS_LEFT  + c * LR_STRIDE + rL * D_ + d] : 0.f;
            Rb[rr][d] = (rR < Mdim) ? ws[WS_RIGHT + c * LR_STRIDE + rR * D_ + d] : 0.f;
        }
    }
    __syncthreads();
    int rr = tid / 16, cc = tid % 16;
    const float4* lrow = (const float4*)(&Lb[rr][0]);
    const float4* rrow = (const float4*)(&Rb[cc][0]);
    float acc = 0.f;
#pragma unroll 8
    for (int d4 = 0; d4 < 64; ++d4) {
        float4 a = lrow[d4], bb = rrow[d4];
        acc += a.x * bb.x + a.y * bb.y + a.z * bb.z + a.w * bb.w;
    }
    int r = r0 + rr, cth = c0 + cc;
    if (r < Mdim && cth < Mdim) {
        if (use_partial) {
            int Cinp = (Cin + 3) & ~3;
            int Jp = 3 * Cinp;
            int W = Jp + ((T + 3) & ~3);
            int rp = (r   < J) ? ((r   % 3) * Cinp + r   / 3) : (Jp + r   - J);
            int op = (cth < J) ? ((cth % 3) * Cinp + cth / 3) : (Jp + cth - J);
            ws[WS_MP + c * MP_STRIDE + rp * W + op] = acc;
        } else {
            ws[WS_MM + c * MM_STRIDE + r * Mdim + cth] = acc;
        }
    }
}

// ---------------- Pack M' into reordered/padded Mp (FALLBACK path only) ----------------
__global__ void pack_kernel(float* __restrict__ ws) {
    int c = blockIdx.x;
    int i, br, l, p, n, Cin, T, J; combo_dims(c, i, br, l, p, n, Cin, T, J);
    int Mdim = J + T;
    int Cinp = (Cin + 3) & ~3;
    int Jp = 3 * Cinp;
    int T4 = (T + 3) & ~3;
    int W = Jp + T4;
    const float* MMc = ws + WS_MM + c * MM_STRIDE;
    float* Mp = ws + WS_MP + c * MP_STRIDE;
    for (int e = blockIdx.y * 256 + threadIdx.x; e < W * W; e += 16 * 256) {
        int r = e / W, o = e % W;
        int srcr = -1, srcc = -1;
        bool brow = false;
        if (r < Jp) {
            int k = r / Cinp, cin = r % Cinp;
            if (cin < Cin) srcr = cin * 3 + k;
        } else {
            int t = r - Jp;
            if (t < T) { srcr = J + t; brow = true; }
        }
        if (o < Jp) {
            int k2 = o / Cinp, cin2 = o % Cinp;
            if (cin2 < Cin) srcc = cin2 * 3 + k2;
        } else {
            int s = o - Jp;
            if (s < T) srcc = J + s;
        }
        float val;
        if (srcr >= 0 && srcc >= 0) val = MMc[srcr * Mdim + srcc];
        else if (brow && o >= Jp && srcc < 0) val = -1e30f;  // padded-s bias: kill in softmax
        else val = 0.f;
        Mp[e] = val;
    }
}

// ---------------- Zero ACC spans (FALLBACK path only; after pack) ----------------
__global__ void zero_acc(float* __restrict__ ws) {
    zero_span(ws, blockIdx.x * 256 + threadIdx.x);
}

// ---------------- LDS size (must mirror attn_body's formulas exactly) ----------------
constexpr int attn_tot(int P, int BR) {
    int N = L_ / P;
    int Cin = BR ? N : P;
    int T = BR ? P : N;
    int Cinp = (Cin + 3) & ~3;
    int Jp = 3 * Cinp;
    int T4 = (T + 3) & ~3;
    int W = Jp + T4;
    int W4 = W / 4;
    int ST = T4 + 1;
    int MC = BR ? (P == 3 ? 12 : 8) : (P == 7 ? 8 : 4);
    int TH = (BR == 0 && P != 5) ? 2 : 1;
    int TSUB = (T + TH - 1) / TH;
    int GR = MC * TSUB + 1;
    int CQ = Cinp / 4;
    int CQP = CQ | 1;
    int MCQ = MC / 4;
    int XTR4 = Cinp * MCQ + 1;
    int SZ_X2A = MC * T * CQP * 4;
    int SZ_G = 4 * W4 * GR;
    int SZ_X2T = T * XTR4 * 4;
    int SZ_MSL = BR ? 0 : Cinp * W;
    int SZ_S = MC * TSUB * ST;
    int OFF_X2T = SZ_X2A + SZ_G;
    int END_A = OFF_X2T + SZ_X2T + SZ_MSL;
    int END_B = OFF_X2T + SZ_S;
    return (END_A > END_B) ? END_A : END_B;
}

// ---------------- Fused attention body (R10/R11 attn2, as __device__) ----------
template<int P, int BR>
__device__ __forceinline__ void attn_body(float* __restrict__ smem,
                                          const float* __restrict__ ws,
                                          float* __restrict__ wsw,
                                          const int b, const int l, const int zz) {
    constexpr int N    = L_ / P;
    constexpr int Cin  = BR ? N : P;
    constexpr int T    = BR ? P : N;
    constexpr int Cinp = (Cin + 3) & ~3;
    constexpr int Jp   = 3 * Cinp;
    constexpr int JP4  = Jp / 4;
    constexpr int T4   = (T + 3) & ~3;
    constexpr int W    = Jp + T4;
    constexpr int W4   = W / 4;
    constexpr int ST   = T4 + 1;
    constexpr int II   = (P - 3) / 2;
    constexpr int MC   = BR ? (P == 3 ? 12 : 8) : (P == 7 ? 8 : 4);
    constexpr int TH   = (BR == 0 && P != 5) ? 2 : 1;     // t-split: <3,0> and <7,0>
    constexpr int TSUB = (T + TH - 1) / TH;               // rows per t-half
    constexpr int GR   = MC * TSUB + 1;                   // G float4-rows (odd)
    constexpr int NT   = (MC / 4) * TSUB * W4;
    constexpr int TPB  = (NT + 255) / 256;
    constexpr int MCQ  = MC / 4;
    constexpr int CQ   = Cinp / 4;
    constexpr int CQP  = CQ | 1;                  // padded X2A row stride (float4s, odd)
    constexpr int S4N  = T4 / 4;
    constexpr int XTR4 = Cinp * MCQ + 1;          // padded X2T row stride (float4s, odd)

    // LDS layout: [X2A][G^T][X2T][MSL(BR==0)]; S overlays X2T(+MSL) after G-phase
    constexpr int OFF_X2A = 0;
    constexpr int SZ_X2A  = MC * T * CQP * 4;
    constexpr int OFF_G   = OFF_X2A + SZ_X2A;
    constexpr int SZ_G    = 4 * W4 * GR;          // transposed: [W4][GR] float4s
    constexpr int OFF_X2T = OFF_G + SZ_G;
    constexpr int SZ_X2T  = T * XTR4 * 4;
    constexpr int OFF_MSL = OFF_X2T + SZ_X2T;
    constexpr int OFF_S   = OFF_X2T;              // X2T (+MSL) dead after G-phase
    static_assert(attn_tot(P, BR) * 4 <= 65536, "LDS budget");

    const int tid = threadIdx.x;
    const int sp = zz / TH;
    const int th = zz % TH;
    const int t0 = th * TSUB;
    const int TC = (T - t0 < TSUB) ? (T - t0) : TSUB;     // valid t rows this block
    const int c = II * 6 + BR * 3 + l;
    const int m0 = sp * MC;
    const int vm = (M_ - m0 < MC) ? (M_ - m0) : MC;

    const float*  Mpg  = ws + WS_MP + c * MP_STRIDE;
    const float4* Mpg4 = (const float4*)Mpg;

    // ---- stage X2A: [mc][trow][cin..pad], per-trow stride CQP float4 ----
    for (int e = tid; e < MC * T * CQP * 4; e += 256) {
        int cin  = e % (CQP * 4);
        int trow = (e / (CQP * 4)) % T;
        int mcol = e / (CQP * 4 * T);
        float v = 0.f;
        if (cin < Cin && m0 + mcol < M_)
            v = ws[WS_XT + (size_t)(b * M_ + m0 + mcol) * L_ + trow * Cin + cin];
        smem[OFF_X2A + e] = v;
    }
    // ---- stage X2T: [trow]([cin][mcol] + pad), per-trow stride XTR4 float4 ----
    for (int e = tid; e < T * XTR4 * 4; e += 256) {
        int w    = e % (XTR4 * 4);
        int trow = e / (XTR4 * 4);
        float v = 0.f;
        if (w < Cinp * MC) {
            int mcol = w % MC, cin = w / MC;
            if (cin < Cin && m0 + mcol < M_)
                v = ws[WS_XT + (size_t)(b * M_ + m0 + mcol) * L_ + trow * Cin + cin];
        }
        smem[OFF_X2T + e] = v;
    }
    __syncthreads();

    const float4* X2T4 = (const float4*)(smem + OFF_X2T);
    const float4* X2A4 = (const float4*)(smem + OFF_X2A);
    float4*       MSL4 = (float4*)(smem + OFF_MSL);
    float4*       G4w  = (float4*)(smem + OFF_G);
    const float4* G4   = (const float4*)(smem + OFF_G);

    // ---- G-phase: register-tiled GEMM over this block's t rows ----
    float a[TPB][4][4];
#pragma unroll
    for (int tt = 0; tt < TPB; ++tt) {
        int q = tid + tt * 256;
        if (q < NT) {
            int o4 = q % W4, tl = (q / W4) % TSUB;
            if (tl < TC) {
                float4 bv = Mpg4[(Jp + t0 + tl) * W4 + o4];
#pragma unroll
                for (int am = 0; am < 4; ++am) {
                    a[tt][am][0] = bv.x; a[tt][am][1] = bv.y;
                    a[tt][am][2] = bv.z; a[tt][am][3] = bv.w;
                }
            }
        }
    }
    if constexpr (BR == 0) {
        // MSL LDS staging per k (tiny: Cinp*W4 <= 96 float4s)
        for (int k = 0; k < 3; ++k) {
            for (int e = tid; e < Cinp * W4; e += 256)
                MSL4[e] = Mpg4[k * Cinp * W4 + e];
            __syncthreads();
#pragma unroll
            for (int tt = 0; tt < TPB; ++tt) {
                int q = tid + tt * 256;
                if (q < NT) {
                    int o4 = q % W4, tl = (q / W4) % TSUB, m4 = q / (W4 * TSUB);
                    if (tl < TC) {
                        int trow = t0 + tl + k - 1;
                        if (trow < 0) trow += T;
                        if (trow >= T) trow -= T;
                        const float4* xp = X2T4 + trow * XTR4 + m4;
                        const float4* mp = MSL4 + o4;
#pragma unroll 4
                        for (int cin = 0; cin < Cinp; ++cin) {
                            float4 x4 = xp[cin * MCQ];
                            float4 mv = mp[cin * W4];
#pragma unroll
                            for (int aq = 0; aq < 4; ++aq) {
                                float m = (aq == 0) ? mv.x : (aq == 1) ? mv.y
                                        : (aq == 2) ? mv.z : mv.w;
                                a[tt][0][aq] += x4.x * m;
                                a[tt][1][aq] += x4.y * m;
                                a[tt][2][aq] += x4.z * m;
                                a[tt][3][aq] += x4.w * m;
                            }
                        }
                    }
                }
            }
            __syncthreads();
        }
    } else {
        __syncthreads();
#pragma unroll
        for (int k = 0; k < 3; ++k) {
#pragma unroll
            for (int tt = 0; tt < TPB; ++tt) {
                int q = tid + tt * 256;
                if (q < NT) {
                    int o4 = q % W4, tl = (q / W4) % TSUB, m4 = q / (W4 * TSUB);
                    if (tl < TC) {
                        int trow = t0 + tl + k - 1;
                        if (trow < 0) trow += T;
                        if (trow >= T) trow -= T;
                        const float4* xp = X2T4 + trow * XTR4 + m4;
                        const float4* mp = Mpg4 + k * Cinp * W4 + o4;   // GLOBAL (L2)
#pragma unroll 4
                        for (int cin = 0; cin < Cinp; ++cin) {
                            float4 x4 = xp[cin * MCQ];
                            float4 mv = mp[cin * W4];
#pragma unroll
                            for (int aq = 0; aq < 4; ++aq) {
                                float m = (aq == 0) ? mv.x : (aq == 1) ? mv.y
                                        : (aq == 2) ? mv.z : mv.w;
                                a[tt][0][aq] += x4.x * m;
                                a[tt][1][aq] += x4.y * m;
                                a[tt][2][aq] += x4.z * m;
                                a[tt][3][aq] += x4.w * m;
                            }
                        }
                    }
                }
            }
        }
    }
#pragma unroll
    for (int tt = 0; tt < TPB; ++tt) {
        int q = tid + tt * 256;
        if (q < NT) {
            int o4 = q % W4, tl = (q / W4) % TSUB, m4 = q / (W4 * TSUB);
            if (tl < TC) {
#pragma unroll
                for (int am = 0; am < 4; ++am) {
                    float4 o;
                    o.x = a[tt][am][0]; o.y = a[tt][am][1];
                    o.z = a[tt][am][2]; o.w = a[tt][am][3];
                    G4w[o4 * GR + (m4 * 4 + am) * TSUB + tl] = o;   // transposed
                }
            }
        }
    }
    __syncthreads();

    // ---- S-phase: tl-fastest lanes; register halo over the 6 X2A rows ----
    for (int it = tid; it < MC * TSUB * S4N; it += 256) {
        int tl = it % TSUB;
        int s4 = (it / TSUB) % S4N;
        int mc = it / (TSUB * S4N);
        if (tl >= TC) continue;
        int mrow = mc * TSUB + tl;
        float4 bi = G4[(JP4 + s4) * GR + mrow];                     // transposed
        float acc[4] = {bi.x, bi.y, bi.z, bi.w};
#pragma unroll 2
        for (int cinq = 0; cinq < CQ; ++cinq) {
            float4 xr[6];
#pragma unroll
            for (int kk = 0; kk < 6; ++kk) {
                int r = s4 * 4 - 1 + kk;
                if (r < 0) r += T;
                if (r >= T) r -= T;
                xr[kk] = X2A4[(mc * T + r) * CQP + cinq];
            }
#pragma unroll
            for (int k = 0; k < 3; ++k) {
                float4 g = G4[(k * CQ + cinq) * GR + mrow];         // transposed
#pragma unroll
                for (int q = 0; q < 4; ++q) {
                    float4 x4 = xr[q + k];
                    acc[q] += g.x * x4.x + g.y * x4.y + g.z * x4.z + g.w * x4.w;
                }
            }
        }
#pragma unroll
        for (int q = 0; q < 4; ++q)
            smem[OFF_S + (mc * TSUB + tl) * ST + s4 * 4 + q] = 0.0625f * acc[q];
    }
    __syncthreads();

    // ---- register single-pass softmax (reads T4, writes T; pads exp->0) ----
    for (int rid = tid; rid < MC * TSUB; rid += 256) {
        int mc = rid / TSUB, tl = rid % TSUB;
        if (tl >= TC) continue;
        int base = OFF_S + (mc * TSUB + tl) * ST;
        float pr[T4];
#pragma unroll
        for (int s = 0; s < T4; ++s) pr[s] = smem[base + s];
        float mx = -1e30f;
#pragma unroll
        for (int s = 0; s < T4; ++s) mx = fmaxf(mx, pr[s]);
        float sum = 0.f;
#pragma unroll
        for (int s = 0; s < T4; ++s) { pr[s] = __expf(pr[s] - mx); sum += pr[s]; }
        float inv = 1.f / sum;
#pragma unroll
        for (int s = 0; s < T; ++s) smem[base + s] = pr[s] * inv;
    }
    __syncthreads();

    float* accp = wsw + c_accws[c] + b * T * T;
    for (int e = tid; e < TC * T; e += 256) {
        int tl = e / T, s = e % T;
        float v = 0.f;
        for (int mc = 0; mc < vm; ++mc)
            v += smem[OFF_S + (mc * TSUB + tl) * ST + s];
        atomicAdd(&accp[(t0 + tl) * T + s], v);
    }
}

// ---------------- Single-variant wrapper (P=5 family) ----------------
template<int P, int BR>
__global__ __launch_bounds__(256) void attn2(const float* __restrict__ ws,
                                             float* __restrict__ wsw) {
    __shared__ __align__(16) float smem[attn_tot(P, BR)];
    attn_body<P, BR>(smem, ws, wsw, blockIdx.x, blockIdx.y, blockIdx.z);
}

// ---------------- Paired wrapper (P=3, P=7): BR0 blocks first, BR1 backfill ---
template<int P>
__global__ __launch_bounds__(256) void attn_pair(const float* __restrict__ ws,
                                                 float* __restrict__ wsw) {
    constexpr int Z0 = (P == 3) ? 28 : 14;   // BR0 z-count (TH=2 both)
    constexpr int T0 = attn_tot(P, 0);
    constexpr int T1 = attn_tot(P, 1);
    constexpr int MAXTOT = (T0 > T1) ? T0 : T1;
    __shared__ __align__(16) float smem[MAXTOT];
    int z = blockIdx.z;
    if (z < Z0) attn_body<P, 0>(smem, ws, wsw, blockIdx.x, blockIdx.y, z);
    else        attn_body<P, 1>(smem, ws, wsw, blockIdx.x, blockIdx.y, z - Z0);
}

// ---------------- Expand accumulated means to the full output ----------------
template<int P, int BR>
__device__ __forceinline__ void expand_body(const float* __restrict__ acc,
                                            float* __restrict__ outp) {
    constexpr int T = BR ? P : (L_ / P);
    for (int idx = threadIdx.x; idx < L_ * L_; idx += 256) {
        int r = idx / L_, c2 = idx % L_;
        int rt = BR ? (r % P) : (r / P);
        int ct = BR ? (c2 % P) : (c2 / P);
        outp[idx] = acc[rt * T + ct];
    }
}

__global__ __launch_bounds__(256) void expand_kernel(const float* __restrict__ ws,
                                                     float* __restrict__ out) {
    int c = blockIdx.x, b = blockIdx.y;
    int i = c / 6, br = (c % 6) / 3, l = c % 3;
    int p = 3 + 2 * i;
    int T = br ? p : (L_ / p);
    __shared__ float sAcc[1232];
    int abase = c_accws[c] + b * T * T;
    for (int idx = threadIdx.x; idx < T * T; idx += 256)
        sAcc[idx] = ws[abase + idx] * (1.f / (float)M_);
    __syncthreads();
    float* outp = out + ((size_t)(br * 9 + i * 3 + l) * B_ + (size_t)b) * (size_t)(L_ * L_);
    int key = i * 2 + br;
    switch (key) {
        case 0: expand_body<3, 0>(sAcc, outp); break;
        case 1: expand_body<3, 1>(sAcc, outp); break;
        case 2: expand_body<5, 0>(sAcc, outp); break;
        case 3: expand_body<5, 1>(sAcc, outp); break;
        case 4: expand_body<7, 0>(sAcc, outp); break;
        case 5: expand_body<7, 1>(sAcc, outp); break;
    }
}

extern "C" void kernel_launch(void* const* d_in, const int* in_sizes, int n_in,
                              void* d_out, int out_size, void* d_ws, size_t ws_size,
                              hipStream_t stream) {
    const float* x   = (const float*)d_in[0];
    const float* cp0 = (const float*)d_in[1];
    const float* cn0 = (const float*)d_in[2];
    const float* cp1 = (const float*)d_in[3];
    const float* cn1 = (const float*)d_in[4];
    const float* cp2 = (const float*)d_in[5];
    const float* cn2 = (const float*)d_in[6];
    const float* Wq  = (const float*)d_in[7];
    const float* bq  = (const float*)d_in[8];
    const float* Wk  = (const float*)d_in[9];
    const float* bk  = (const float*)d_in[10];
    float* ws = (float*)d_ws;
    float* out = (float*)d_out;

    const int use_partial = (ws_size >= WS_NEED_BYTES) ? 1 : 0;

    hipLaunchKernelGGL(prep_kernel, dim3(PREP_BLOCKS), dim3(256), 0, stream, x, ws);
    if (use_partial) {
        hipLaunchKernelGGL(lr2_kernel, dim3(NCOMBO, 14, 4), dim3(256), 0, stream,
                           cp0, cn0, cp1, cn1, cp2, cn2, Wq, bq, Wk, bk, ws);
    } else {
        hipLaunchKernelGGL(lr_kernel, dim3(NCOMBO, 27), dim3(256), 0, stream,
                           cp0, cn0, cp1, cn1, cp2, cn2, Wq, bq, Wk, bk, ws);
    }
    hipLaunchKernelGGL(mm_kernel, dim3(NCOMBO, 49), dim3(256), 0, stream, ws, use_partial);
    if (!use_partial) {
        // fallback: mm wrote WS_MM; reorder into Mp, then zero ACC spans
        // (they overlay RIGHT/MM which lr/mm used after prep's zeroing).
        hipLaunchKernelGGL(pack_kernel, dim3(NCOMBO, 16), dim3(256), 0, stream, ws);
        hipLaunchKernelGGL(zero_acc, dim3(Z_BLOCKS), dim3(256), 0, stream, ws);
    }

    // Paired dispatches: z partitioned BR0-first (BR1 backfills the tail).
    // P=3 pair: LDS union identical (27136B). P=5 kept separate (union
    // would cost <5,1> 7->5 blocks/CU). P=7 union 24.8KB (<7,1> 7->6).
    hipLaunchKernelGGL((attn_pair<3>), dim3(B_, 3, 33), dim3(256), 0, stream, ws, ws);
    hipLaunchKernelGGL((attn2<5, 0>),  dim3(B_, 3, 14), dim3(256), 0, stream, ws, ws);
    hipLaunchKernelGGL((attn2<5, 1>),  dim3(B_, 3, 7),  dim3(256), 0, stream, ws, ws);
    hipLaunchKernelGGL((attn_pair<7>), dim3(B_, 3, 21), dim3(256), 0, stream, ws, ws);

    hipLaunchKernelGGL(expand_kernel, dim3(NCOMBO, B_), dim3(256), 0, stream, ws, out);
}

// Round 13
// 423.493 us; speedup vs baseline: 1.0380x; 1.0203x over previous
//
#include <hip/hip_runtime.h>
#include <hip/hip_bf16.h>

// Problem constants
#define B_ 128
#define L_ 105
#define M_ 55
#define D_ 256
#define NCOMBO 18   // 3 patches x 2 branches x 3 layers

// Workspace layout (float offsets)
#define WS_XT    0          // normalized x^T: [B*M][105] = 739200
#define WS_PE    739200     // pos-embed tables: 86*256 = 22016
#define WS_LEFT  761216     // 18 * 27648 (fallback path; MP overlays after mm)
#define WS_RIGHT 1258880    // 18 * 27648 (ACC-B overlays after mm)
#define WS_MM    1756544    // 18 * 11664
#define WS_MP    761216     // 18 * 12544 (over LEFT, after mm)
#define LR_STRIDE 27648
#define MM_STRIDE 11664
#define MP_STRIDE 12544

// ACC split: combos 0-12 at WS_ACC_B (ends 1940480 < WS_LRP); combos 13-17
// in the MP..RIGHT gap at WS_ACC_A (ends 1063424 < WS_RIGHT). Neither span
// overlaps LRP -> zeroing can happen in prep (partial path).
#define WS_ACC_A 987008
#define WS_ACC_B 1258880
#define ZA_F4 19104          // 76416 floats / 4  (combos 13-17)
#define ZB_F4 170400         // 681600 floats / 4 (combos 0-12)
#define Z_TOT_F4 (ZA_F4 + ZB_F4)
#define Z_BLOCKS ((Z_TOT_F4 + 255) / 256)   // 741

// K-split partial region (only used when ws_size is large enough)
#define WS_LRP        1966592
#define LRP_KZ_STRIDE 27648
#define LRP_C_STRIDE  110592
#define LRP_HALF      1990656
#define WS_NEED_BYTES ((size_t)(WS_LRP + 2 * LRP_HALF) * 4)

__constant__ int c_peOff[6] = {0, 35, 38, 59, 64, 79};
// acc float-offset per combo (split layout; see above)
__constant__ int c_accws[18] = {
    1258880, 1415680, 1572480,           // <3,0> l=0..2
    1729280, 1730432, 1731584,           // <3,1>
    1732736, 1789184, 1845632,           // <5,0>
    1902080, 1905280, 1908480,           // <5,1>
    1911680,                             // <7,0> l=0
    987008, 1015808,                     // <7,0> l=1..2 (gap region)
    1044608, 1050880, 1057152};          // <7,1> (gap region)

__device__ __forceinline__ void combo_dims(int c, int& i, int& br, int& l,
                                           int& p, int& n, int& Cin, int& T, int& J) {
    i = c / 6; br = (c % 6) / 3; l = c % 3;
    p = 3 + 2 * i;
    n = L_ / p;
    Cin = br ? n : p;
    T   = br ? p : n;
    J = 3 * Cin;
}

__device__ __forceinline__ void zero_span(float* __restrict__ ws, int idx) {
    float4 z; z.x = 0.f; z.y = 0.f; z.z = 0.f; z.w = 0.f;
    if (idx < ZA_F4) ((float4*)(ws + WS_ACC_A))[idx] = z;
    else if (idx < Z_TOT_F4) ((float4*)(ws + WS_ACC_B))[idx - ZA_F4] = z;
}

// ---------------- prep: RevIN (coalesced, 1 b/block) + PE + pad prefill + ACC zero ----
#define PREP_REVIN_BLOCKS B_      // one block per b; [L][M] tile staged in LDS
#define PREP_PE_END   (PREP_REVIN_BLOCKS + 6)
#define PREP_PAD_END  (PREP_PE_END + NCOMBO)
#define PREP_BLOCKS   (PREP_PAD_END + Z_BLOCKS)
__global__ __launch_bounds__(256) void prep_kernel(const float* __restrict__ x,
                                                   float* __restrict__ ws) {
    __shared__ float xs[L_ * M_ + 2 * M_];   // tile + mean + rstd
    int bid = blockIdx.x;
    int tid = threadIdx.x;
    if (bid < PREP_REVIN_BLOCKS) {
        int b = bid;
        float* sm = xs + L_ * M_;
        float* sr = sm + M_;
        // coalesced load of the contiguous [L][M] tile
        for (int e = tid; e < L_ * M_; e += 256)
            xs[e] = x[(size_t)b * (L_ * M_) + e];
        __syncthreads();
        if (tid < M_) {
            float s = 0.f, s2 = 0.f;
            for (int t = 0; t < L_; ++t) {
                float v = xs[t * M_ + tid];   // stride 55: conflict-free
                s += v; s2 += v * v;
            }
            float mean = s * (1.f / L_);
            float var  = s2 * (1.f / L_) - mean * mean;
            sm[tid] = mean;
            sr[tid] = rsqrtf(var + 1e-5f);
        }
        __syncthreads();
        // transposed, coalesced write: ws[(b*M+m)*L + t]
        for (int e = tid; e < L_ * M_; e += 256) {
            int m = e / L_, t = e % L_;
            ws[WS_XT + (size_t)(b * M_ + m) * L_ + t] = (xs[t * M_ + m] - sm[m]) * sr[m];
        }
    } else if (bid < PREP_PE_END) {
        int bi = bid - PREP_REVIN_BLOCKS;          // 0..5
        int i = bi / 2, br = bi % 2;
        int p = 3 + 2 * i, n = L_ / p;
        int T = br ? p : n;
        int d = tid;
        float divv = expf(-(float)(d & ~1) * (logf(10000.f) / (float)D_));
        float* base = ws + WS_PE + c_peOff[bi] * D_;
        for (int t = 0; t < T; ++t) {
            float arg = (float)t * divv;
            base[t * D_ + d] = (d & 1) ? cosf(arg) : sinf(arg);
        }
    } else if (bid < PREP_PAD_END) {
        int c = bid - PREP_PE_END;                 // 0..17: Mp pad prefill
        int i, br, l, p, n, Cin, T, J; combo_dims(c, i, br, l, p, n, Cin, T, J);
        int Cinp = (Cin + 3) & ~3;
        int Jp = 3 * Cinp;
        int T4 = (T + 3) & ~3;
        int W = Jp + T4;
        float* Mp = ws + WS_MP + c * MP_STRIDE;
        for (int e = tid; e < W * W; e += 256) {
            int r = e / W, o = e % W;
            bool vr   = (r < Jp) ? ((r % Cinp) < Cin) : (r - Jp < T);
            bool brow = (r >= Jp) && (r - Jp < T);
            bool vc   = (o < Jp) ? ((o % Cinp) < Cin) : (o - Jp < T);
            if (!(vr && vc))
                Mp[e] = (brow && o >= Jp && !vc) ? -1e30f : 0.f;
        }
    } else {
        // ACC zero (safe pre-lr2: spans are disjoint from LRP/MP/XT/PE).
        int idx = (bid - PREP_PAD_END) * 256 + tid;
        zero_span(ws, idx);
    }
}

// ---------------- lr2: K-split x4, 8-row tiles, unique-writer partials ----------------
__global__ __launch_bounds__(256) void lr2_kernel(
                          const float* __restrict__ w0, const float* __restrict__ w1,
                          const float* __restrict__ w2c, const float* __restrict__ w3,
                          const float* __restrict__ w4, const float* __restrict__ w5,
                          const float* __restrict__ Wq, const float* __restrict__ bq,
                          const float* __restrict__ Wk, const float* __restrict__ bk,
                          float* __restrict__ ws) {
    int c = blockIdx.x;
    int i, br, l, p, n, Cin, T, J; combo_dims(c, i, br, l, p, n, Cin, T, J);
    int Mdim = J + T;
    int r0 = blockIdx.y * 8;
    if (r0 >= Mdim) return;
    int kz = blockIdx.z;
    int d0 = kz * 64;
    int wi = i * 2 + br;
    const float* conv = (wi == 0) ? w0 : (wi == 1) ? w1 : (wi == 2) ? w2c
                       : (wi == 3) ? w3 : (wi == 4) ? w4 : w5;
    __shared__ float S[8][64];
    int tid = threadIdx.x;
    for (int idx = tid; idx < 8 * 64; idx += 256) {
        int rr = idx >> 6, dd = idx & 63;
        int row = r0 + rr; float val = 0.f;
        int d = d0 + dd;
        if (row < J) val = conv[d * J + row];
        else if (row < Mdim) val = ws[WS_PE + (c_peOff[wi] + (row - J)) * D_ + d];
        S[rr][dd] = val;
    }
    __syncthreads();
    const float* wqp = Wq + l * D_ * D_;
    const float* wkp = Wk + l * D_ * D_;
    float accL[8], accR[8];
#pragma unroll
    for (int rr = 0; rr < 8; ++rr) { accL[rr] = 0.f; accR[rr] = 0.f; }
    int o = tid;
#pragma unroll 8
    for (int dd = 0; dd < 64; ++dd) {
        int d = d0 + dd;
        float wqv = wqp[d * D_ + o];
        float wkv = wkp[d * D_ + o];
#pragma unroll
        for (int rr = 0; rr < 8; ++rr) {
            float sv = S[rr][dd];
            accL[rr] += sv * wqv;
            accR[rr] += sv * wkv;
        }
    }
    float bqv = (kz == 0) ? bq[l * D_ + o] : 0.f;
    float bkv = (kz == 0) ? bk[l * D_ + o] : 0.f;
    float* Lp = ws + WS_LRP + c * LRP_C_STRIDE + kz * LRP_KZ_STRIDE;
    float* Rp = Lp + LRP_HALF;
#pragma unroll
    for (int rr = 0; rr < 8; ++rr) {
        int row = r0 + rr;
        if (row < Mdim) {
            float aq = (row >= J) ? bqv : 0.f;
            float ak = (row >= J) ? bkv : 0.f;
            Lp[row * D_ + o] = accL[rr] + aq;
            Rp[row * D_ + o] = accR[rr] + ak;
        }
    }
}

// ---------------- Fallback lr: 4 rows per block, full K ----------------
__global__ __launch_bounds__(256) void lr_kernel(
                          const float* __restrict__ w0, const float* __restrict__ w1,
                          const float* __restrict__ w2c, const float* __restrict__ w3,
                          const float* __restrict__ w4, const float* __restrict__ w5,
                          const float* __restrict__ Wq, const float* __restrict__ bq,
                          const float* __restrict__ Wk, const float* __restrict__ bk,
                          float* __restrict__ ws) {
    int c = blockIdx.x;
    int i, br, l, p, n, Cin, T, J; combo_dims(c, i, br, l, p, n, Cin, T, J);
    int Mdim = J + T;
    int r0 = blockIdx.y * 4;
    if (r0 >= Mdim) return;
    int wi = i * 2 + br;
    const float* conv = (wi == 0) ? w0 : (wi == 1) ? w1 : (wi == 2) ? w2c
                       : (wi == 3) ? w3 : (wi == 4) ? w4 : w5;
    __shared__ float S[4][256];
    int tid = threadIdx.x;
    for (int idx = tid; idx < 4 * 256; idx += 256) {
        int rr = idx >> 8, dd = idx & 255;
        int row = r0 + rr; float val = 0.f;
        if (row < J) val = conv[dd * J + row];
        else if (row < Mdim) val = ws[WS_PE + (c_peOff[wi] + (row - J)) * D_ + dd];
        S[rr][dd] = val;
    }
    __syncthreads();
    const float* wqp = Wq + l * D_ * D_;
    const float* wkp = Wk + l * D_ * D_;
    float accL[4], accR[4];
#pragma unroll
    for (int rr = 0; rr < 4; ++rr) { accL[rr] = 0.f; accR[rr] = 0.f; }
    int o = tid;
#pragma unroll 8
    for (int d = 0; d < D_; ++d) {
        float wqv = wqp[d * D_ + o];
        float wkv = wkp[d * D_ + o];
#pragma unroll
        for (int rr = 0; rr < 4; ++rr) {
            float sv = S[rr][d];
            accL[rr] += sv * wqv;
            accR[rr] += sv * wkv;
        }
    }
    float bqv = bq[l * D_ + o], bkv = bk[l * D_ + o];
#pragma unroll
    for (int rr = 0; rr < 4; ++rr) {
        int row = r0 + rr;
        if (row < Mdim) {
            float aq = (row >= J) ? bqv : 0.f;
            float ak = (row >= J) ? bkv : 0.f;
            ws[WS_LEFT  + c * LR_STRIDE + row * D_ + o] = accL[rr] + aq;
            ws[WS_RIGHT + c * LR_STRIDE + row * D_ + o] = accR[rr] + ak;
        }
    }
}

// ---------------- M' = Left @ Right^T ----------------
// Partial path: scatter-writes DIRECTLY into packed Mp (pads prefilled by
// prep) — the pack dispatch is skipped. Fallback: writes WS_MM as before.
__global__ void mm_kernel(float* __restrict__ ws, int use_partial) {
    int c = blockIdx.x;
    int i, br, l, p, n, Cin, T, J; combo_dims(c, i, br, l, p, n, Cin, T, J);
    int Mdim = J + T;
    int tr = blockIdx.y / 7, tc = blockIdx.y % 7;
    int r0 = tr * 16, c0 = tc * 16;
    if (r0 >= Mdim || c0 >= Mdim) return;
    __shared__ __align__(16) float Lb[16][260], Rb[16][260];
    int tid = threadIdx.x;
    if (use_partial) {
        const float* Lp = ws + WS_LRP + c * LRP_C_STRIDE;
        const float* Rp = Lp + LRP_HALF;
        for (int idx = tid; idx < 16 * 256; idx += 256) {
            int rr = idx >> 8, d = idx & 255;
            int rL = r0 + rr, rR = c0 + rr;
            float lv = 0.f, rv = 0.f;
            if (rL < Mdim) {
                int base = rL * D_ + d;
                lv = Lp[base] + Lp[base + LRP_KZ_STRIDE]
                   + Lp[base + 2 * LRP_KZ_STRIDE] + Lp[base + 3 * LRP_KZ_STRIDE];
            }
            if (rR < Mdim) {
                int base = rR * D_ + d;
                rv = Rp[base] + Rp[base + LRP_KZ_STRIDE]
                   + Rp[base + 2 * LRP_KZ_STRIDE] + Rp[base + 3 * LRP_KZ_STRIDE];
            }
            Lb[rr][d] = lv; Rb[rr][d] = rv;
        }
    } else {
        for (int idx = tid; idx < 16 * 256; idx += 256) {
            int rr = idx >> 8, d = idx & 255;
            int rL = r0 + rr, rR = c0 + rr;
            Lb[rr][d] = (rL < Mdim) ? ws[WS_LEFT  + c * LR_STRIDE + rL * D_ + d] : 0.f;
            Rb[rr][d] = (rR < Mdim) ? ws[WS_RIGHT + c * LR_STRIDE + rR * D_ + d] : 0.f;
        }
    }
    __syncthreads();
    int rr = tid / 16, cc = tid % 16;
    const float4* lrow = (const float4*)(&Lb[rr][0]);
    const float4* rrow = (const float4*)(&Rb[cc][0]);
    float acc = 0.f;
#pragma unroll 8
    for (int d4 = 0; d4 < 64; ++d4) {
        float4 a = lrow[d4], bb = rrow[d4];
        acc += a.x * bb.x + a.y * bb.y + a.z * bb.z + a.w * bb.w;
    }
    int r = r0 + rr, cth = c0 + cc;
    if (r < Mdim && cth < Mdim) {
        if (use_partial) {
            int Cinp = (Cin + 3) & ~3;
            int Jp = 3 * Cinp;
            int W = Jp + ((T + 3) & ~3);
            int rp = (r   < J) ? ((r   % 3) * Cinp + r   / 3) : (Jp + r   - J);
            int op = (cth < J) ? ((cth % 3) * Cinp + cth / 3) : (Jp + cth - J);
            ws[WS_MP + c * MP_STRIDE + rp * W + op] = acc;
        } else {
            ws[WS_MM + c * MM_STRIDE + r * Mdim + cth] = acc;
        }
    }
}

// ---------------- Pack M' into reordered/padded Mp (FALLBACK path only) ----------------
__global__ void pack_kernel(float* __restrict__ ws) {
    int c = blockIdx.x;
    int i, br, l, p, n, Cin, T, J; combo_dims(c, i, br, l, p, n, Cin, T, J);
    int Mdim = J + T;
    int Cinp = (Cin + 3) & ~3;
    int Jp = 3 * Cinp;
    int T4 = (T + 3) & ~3;
    int W = Jp + T4;
    const float* MMc = ws + WS_MM + c * MM_STRIDE;
    float* Mp = ws + WS_MP + c * MP_STRIDE;
    for (int e = blockIdx.y * 256 + threadIdx.x; e < W * W; e += 16 * 256) {
        int r = e / W, o = e % W;
        int srcr = -1, srcc = -1;
        bool brow = false;
        if (r < Jp) {
            int k = r / Cinp, cin = r % Cinp;
            if (cin < Cin) srcr = cin * 3 + k;
        } else {
            int t = r - Jp;
            if (t < T) { srcr = J + t; brow = true; }
        }
        if (o < Jp) {
            int k2 = o / Cinp, cin2 = o % Cinp;
            if (cin2 < Cin) srcc = cin2 * 3 + k2;
        } else {
            int s = o - Jp;
            if (s < T) srcc = J + s;
        }
        float val;
        if (srcr >= 0 && srcc >= 0) val = MMc[srcr * Mdim + srcc];
        else if (brow && o >= Jp && srcc < 0) val = -1e30f;  // padded-s bias: kill in softmax
        else val = 0.f;
        Mp[e] = val;
    }
}

// ---------------- Zero ACC spans (FALLBACK path only; after pack) ----------------
__global__ void zero_acc(float* __restrict__ ws) {
    zero_span(ws, blockIdx.x * 256 + threadIdx.x);
}

// ---------------- LDS size (must mirror attn_body's formulas exactly) ----------------
constexpr int attn_tot(int P, int BR) {
    int N = L_ / P;
    int Cin = BR ? N : P;
    int T = BR ? P : N;
    int Cinp = (Cin + 3) & ~3;
    int Jp = 3 * Cinp;
    int T4 = (T + 3) & ~3;
    int W = Jp + T4;
    int W4 = W / 4;
    int ST = T4 + 1;
    int MC = BR ? (P == 3 ? 12 : 8) : (P == 7 ? 8 : 4);
    int TH = (BR == 0 && P != 5) ? 2 : 1;
    int TSUB = (T + TH - 1) / TH;
    int GR = MC * TSUB + 1;
    int CQ = Cinp / 4;
    int CQP = CQ | 1;
    int MCQ = MC / 4;
    int XTR4 = Cinp * MCQ + 1;
    int SZ_X2A = MC * T * CQP * 4;
    int SZ_G = 4 * W4 * GR;
    int SZ_X2T = T * XTR4 * 4;
    int SZ_MSL = BR ? 0 : Cinp * W;
    int SZ_S = MC * TSUB * ST;
    int OFF_X2T = SZ_X2A + SZ_G;
    int END_A = OFF_X2T + SZ_X2T + SZ_MSL;
    int END_B = OFF_X2T + SZ_S;
    return (END_A > END_B) ? END_A : END_B;
}

// ---------------- Fused attention body ----------
template<int P, int BR>
__device__ __forceinline__ void attn_body(float* __restrict__ smem,
                                          const float* __restrict__ ws,
                                          float* __restrict__ wsw,
                                          const int b, const int l, const int zz) {
    constexpr int N    = L_ / P;
    constexpr int Cin  = BR ? N : P;
    constexpr int T    = BR ? P : N;
    constexpr int Cinp = (Cin + 3) & ~3;
    constexpr int Jp   = 3 * Cinp;
    constexpr int JP4  = Jp / 4;
    constexpr int T4   = (T + 3) & ~3;
    constexpr int W    = Jp + T4;
    constexpr int W4   = W / 4;
    constexpr int ST   = T4 + 1;
    constexpr int II   = (P - 3) / 2;
    constexpr int MC   = BR ? (P == 3 ? 12 : 8) : (P == 7 ? 8 : 4);
    constexpr int TH   = (BR == 0 && P != 5) ? 2 : 1;     // t-split: <3,0> and <7,0>
    constexpr int TSUB = (T + TH - 1) / TH;               // rows per t-half
    constexpr int GR   = MC * TSUB + 1;                   // G float4-rows (odd)
    constexpr int NT   = (MC / 4) * TSUB * W4;
    constexpr int TPB  = (NT + 255) / 256;
    constexpr int MCQ  = MC / 4;
    constexpr int CQ   = Cinp / 4;
    constexpr int CQP  = CQ | 1;                  // padded X2A row stride (float4s, odd)
    constexpr int S4N  = T4 / 4;
    constexpr int XTR4 = Cinp * MCQ + 1;          // padded X2T row stride (float4s, odd)

    // LDS layout: [X2A][G^T][X2T][MSL(BR==0)]; S overlays X2T(+MSL) after G-phase
    constexpr int OFF_X2A = 0;
    constexpr int SZ_X2A  = MC * T * CQP * 4;
    constexpr int OFF_G   = OFF_X2A + SZ_X2A;
    constexpr int SZ_G    = 4 * W4 * GR;          // transposed: [W4][GR] float4s
    constexpr int OFF_X2T = OFF_G + SZ_G;
    constexpr int SZ_X2T  = T * XTR4 * 4;
    constexpr int OFF_MSL = OFF_X2T + SZ_X2T;
    constexpr int OFF_S   = OFF_X2T;              // X2T (+MSL) dead after G-phase
    static_assert(attn_tot(P, BR) * 4 <= 65536, "LDS budget");

    const int tid = threadIdx.x;
    const int sp = zz / TH;
    const int th = zz % TH;
    const int t0 = th * TSUB;
    const int TC = (T - t0 < TSUB) ? (T - t0) : TSUB;     // valid t rows this block
    const int c = II * 6 + BR * 3 + l;
    const int m0 = sp * MC;
    const int vm = (M_ - m0 < MC) ? (M_ - m0) : MC;

    const float*  Mpg  = ws + WS_MP + c * MP_STRIDE;
    const float4* Mpg4 = (const float4*)Mpg;

    // ---- stage X2A: [mc][trow][cin..pad], per-trow stride CQP float4 ----
    for (int e = tid; e < MC * T * CQP * 4; e += 256) {
        int cin  = e % (CQP * 4);
        int trow = (e / (CQP * 4)) % T;
        int mcol = e / (CQP * 4 * T);
        float v = 0.f;
        if (cin < Cin && m0 + mcol < M_)
            v = ws[WS_XT + (size_t)(b * M_ + m0 + mcol) * L_ + trow * Cin + cin];
        smem[OFF_X2A + e] = v;
    }
    // ---- stage X2T: [trow]([cin][mcol] + pad), per-trow stride XTR4 float4 ----
    for (int e = tid; e < T * XTR4 * 4; e += 256) {
        int w    = e % (XTR4 * 4);
        int trow = e / (XTR4 * 4);
        float v = 0.f;
        if (w < Cinp * MC) {
            int mcol = w % MC, cin = w / MC;
            if (cin < Cin && m0 + mcol < M_)
                v = ws[WS_XT + (size_t)(b * M_ + m0 + mcol) * L_ + trow * Cin + cin];
        }
        smem[OFF_X2T + e] = v;
    }
    __syncthreads();

    const float4* X2T4 = (const float4*)(smem + OFF_X2T);
    const float4* X2A4 = (const float4*)(smem + OFF_X2A);
    float4*       MSL4 = (float4*)(smem + OFF_MSL);
    float4*       G4w  = (float4*)(smem + OFF_G);
    const float4* G4   = (const float4*)(smem + OFF_G);

    // ---- G-phase: register-tiled GEMM over this block's t rows ----
    float a[TPB][4][4];
#pragma unroll
    for (int tt = 0; tt < TPB; ++tt) {
        int q = tid + tt * 256;
        if (q < NT) {
            int o4 = q % W4, tl = (q / W4) % TSUB;
            if (tl < TC) {
                float4 bv = Mpg4[(Jp + t0 + tl) * W4 + o4];
#pragma unroll
                for (int am = 0; am < 4; ++am) {
                    a[tt][am][0] = bv.x; a[tt][am][1] = bv.y;
                    a[tt][am][2] = bv.z; a[tt][am][3] = bv.w;
                }
            }
        }
    }
    if constexpr (BR == 0) {
        // MSL LDS staging per k (tiny: Cinp*W4 <= 96 float4s)
        for (int k = 0; k < 3; ++k) {
            for (int e = tid; e < Cinp * W4; e += 256)
                MSL4[e] = Mpg4[k * Cinp * W4 + e];
            __syncthreads();
#pragma unroll
            for (int tt = 0; tt < TPB; ++tt) {
                int q = tid + tt * 256;
                if (q < NT) {
                    int o4 = q % W4, tl = (q / W4) % TSUB, m4 = q / (W4 * TSUB);
                    if (tl < TC) {
                        int trow = t0 + tl + k - 1;
                        if (trow < 0) trow += T;
                        if (trow >= T) trow -= T;
                        const float4* xp = X2T4 + trow * XTR4 + m4;
                        const float4* mp = MSL4 + o4;
#pragma unroll 4
                        for (int cin = 0; cin < Cinp; ++cin) {
                            float4 x4 = xp[cin * MCQ];
                            float4 mv = mp[cin * W4];
#pragma unroll
                            for (int aq = 0; aq < 4; ++aq) {
                                float m = (aq == 0) ? mv.x : (aq == 1) ? mv.y
                                        : (aq == 2) ? mv.z : mv.w;
                                a[tt][0][aq] += x4.x * m;
                                a[tt][1][aq] += x4.y * m;
                                a[tt][2][aq] += x4.z * m;
                                a[tt][3][aq] += x4.w * m;
                            }
                        }
                    }
                }
            }
            __syncthreads();
        }
    } else {
        __syncthreads();
#pragma unroll
        for (int k = 0; k < 3; ++k) {
#pragma unroll
            for (int tt = 0; tt < TPB; ++tt) {
                int q = tid + tt * 256;
                if (q < NT) {
                    int o4 = q % W4, tl = (q / W4) % TSUB, m4 = q / (W4 * TSUB);
                    if (tl < TC) {
                        int trow = t0 + tl + k - 1;
                        if (trow < 0) trow += T;
                        if (trow >= T) trow -= T;
                        const float4* xp = X2T4 + trow * XTR4 + m4;
                        const float4* mp = Mpg4 + k * Cinp * W4 + o4;   // GLOBAL (L2)
#pragma unroll 4
                        for (int cin = 0; cin < Cinp; ++cin) {
                            float4 x4 = xp[cin * MCQ];
                            float4 mv = mp[cin * W4];
#pragma unroll
                            for (int aq = 0; aq < 4; ++aq) {
                                float m = (aq == 0) ? mv.x : (aq == 1) ? mv.y
                                        : (aq == 2) ? mv.z : mv.w;
                                a[tt][0][aq] += x4.x * m;
                                a[tt][1][aq] += x4.y * m;
                                a[tt][2][aq] += x4.z * m;
                                a[tt][3][aq] += x4.w * m;
                            }
                        }
                    }
                }
            }
        }
    }
#pragma unroll
    for (int tt = 0; tt < TPB; ++tt) {
        int q = tid + tt * 256;
        if (q < NT) {
            int o4 = q % W4, tl = (q / W4) % TSUB, m4 = q / (W4 * TSUB);
            if (tl < TC) {
#pragma unroll
                for (int am = 0; am < 4; ++am) {
                    float4 o;
                    o.x = a[tt][am][0]; o.y = a[tt][am][1];
                    o.z = a[tt][am][2]; o.w = a[tt][am][3];
                    G4w[o4 * GR + (m4 * 4 + am) * TSUB + tl] = o;   // transposed
                }
            }
        }
    }
    __syncthreads();

    // ---- S-phase: tl-fastest lanes; register halo over the 6 X2A rows ----
    for (int it = tid; it < MC * TSUB * S4N; it += 256) {
        int tl = it % TSUB;
        int s4 = (it / TSUB) % S4N;
        int mc = it / (TSUB * S4N);
        if (tl >= TC) continue;
        int mrow = mc * TSUB + tl;
        float4 bi = G4[(JP4 + s4) * GR + mrow];                     // transposed
        float acc[4] = {bi.x, bi.y, bi.z, bi.w};
#pragma unroll 2
        for (int cinq = 0; cinq < CQ; ++cinq) {
            float4 xr[6];
#pragma unroll
            for (int kk = 0; kk < 6; ++kk) {
                int r = s4 * 4 - 1 + kk;
                if (r < 0) r += T;
                if (r >= T) r -= T;
                xr[kk] = X2A4[(mc * T + r) * CQP + cinq];
            }
#pragma unroll
            for (int k = 0; k < 3; ++k) {
                float4 g = G4[(k * CQ + cinq) * GR + mrow];         // transposed
#pragma unroll
                for (int q = 0; q < 4; ++q) {
                    float4 x4 = xr[q + k];
                    acc[q] += g.x * x4.x + g.y * x4.y + g.z * x4.z + g.w * x4.w;
                }
            }
        }
#pragma unroll
        for (int q = 0; q < 4; ++q)
            smem[OFF_S + (mc * TSUB + tl) * ST + s4 * 4 + q] = 0.0625f * acc[q];
    }
    __syncthreads();

    // ---- register single-pass softmax (reads T4, writes T; pads exp->0) ----
    for (int rid = tid; rid < MC * TSUB; rid += 256) {
        int mc = rid / TSUB, tl = rid % TSUB;
        if (tl >= TC) continue;
        int base = OFF_S + (mc * TSUB + tl) * ST;
        float pr[T4];
#pragma unroll
        for (int s = 0; s < T4; ++s) pr[s] = smem[base + s];
        float mx = -1e30f;
#pragma unroll
        for (int s = 0; s < T4; ++s) mx = fmaxf(mx, pr[s]);
        float sum = 0.f;
#pragma unroll
        for (int s = 0; s < T4; ++s) { pr[s] = __expf(pr[s] - mx); sum += pr[s]; }
        float inv = 1.f / sum;
#pragma unroll
        for (int s = 0; s < T; ++s) smem[base + s] = pr[s] * inv;
    }
    __syncthreads();

    float* accp = wsw + c_accws[c] + b * T * T;
    for (int e = tid; e < TC * T; e += 256) {
        int tl = e / T, s = e % T;
        float v = 0.f;
        for (int mc = 0; mc < vm; ++mc)
            v += smem[OFF_S + (mc * TSUB + tl) * ST + s];
        atomicAdd(&accp[(t0 + tl) * T + s], v);
    }
}

// ---------------- Single-variant wrapper (<5,0>) ----------------
template<int P, int BR>
__global__ __launch_bounds__(256) void attn2(const float* __restrict__ ws,
                                             float* __restrict__ wsw) {
    __shared__ __align__(16) float smem[attn_tot(P, BR)];
    attn_body<P, BR>(smem, ws, wsw, blockIdx.x, blockIdx.y, blockIdx.z);
}

// ---------------- Paired wrapper (P=3): BR0 first, BR1 backfill ----------------
template<int P>
__global__ __launch_bounds__(256) void attn_pair(const float* __restrict__ ws,
                                                 float* __restrict__ wsw) {
    constexpr int Z0 = (P == 3) ? 28 : 14;   // BR0 z-count (TH=2 both)
    constexpr int T0 = attn_tot(P, 0);
    constexpr int T1 = attn_tot(P, 1);
    constexpr int MAXTOT = (T0 > T1) ? T0 : T1;
    __shared__ __align__(16) float smem[MAXTOT];
    int z = blockIdx.z;
    if (z < Z0) attn_body<P, 0>(smem, ws, wsw, blockIdx.x, blockIdx.y, z);
    else        attn_body<P, 1>(smem, ws, wsw, blockIdx.x, blockIdx.y, z - Z0);
}

// ---------------- Triple wrapper {<7,0>,<7,1>,<5,1>}: LDS union is free ------
__global__ __launch_bounds__(256) void attn_triple(const float* __restrict__ ws,
                                                   float* __restrict__ wsw) {
    constexpr int Ta = attn_tot(7, 0);
    constexpr int Tb = attn_tot(7, 1);
    constexpr int Tc = attn_tot(5, 1);
    constexpr int M1 = (Ta > Tb) ? Ta : Tb;
    constexpr int MAXTOT = (M1 > Tc) ? M1 : Tc;   // 5380 fl = 21.5KB -> 7 blk/CU
    __shared__ __align__(16) float smem[MAXTOT];
    int z = blockIdx.z;
    if (z < 14)      attn_body<7, 0>(smem, ws, wsw, blockIdx.x, blockIdx.y, z);
    else if (z < 21) attn_body<7, 1>(smem, ws, wsw, blockIdx.x, blockIdx.y, z - 14);
    else             attn_body<5, 1>(smem, ws, wsw, blockIdx.x, blockIdx.y, z - 21);
}

// ---------------- Expand accumulated means to the full output ----------------
template<int P, int BR>
__device__ __forceinline__ void expand_body(const float* __restrict__ acc,
                                            float* __restrict__ outp) {
    constexpr int T = BR ? P : (L_ / P);
    for (int idx = threadIdx.x; idx < L_ * L_; idx += 256) {
        int r = idx / L_, c2 = idx % L_;
        int rt = BR ? (r % P) : (r / P);
        int ct = BR ? (c2 % P) : (c2 / P);
        outp[idx] = acc[rt * T + ct];
    }
}

__global__ __launch_bounds__(256) void expand_kernel(const float* __restrict__ ws,
                                                     float* __restrict__ out) {
    int c = blockIdx.x, b = blockIdx.y;
    int i = c / 6, br = (c % 6) / 3, l = c % 3;
    int p = 3 + 2 * i;
    int T = br ? p : (L_ / p);
    __shared__ float sAcc[1232];
    int abase = c_accws[c] + b * T * T;
    for (int idx = threadIdx.x; idx < T * T; idx += 256)
        sAcc[idx] = ws[abase + idx] * (1.f / (float)M_);
    __syncthreads();
    float* outp = out + ((size_t)(br * 9 + i * 3 + l) * B_ + (size_t)b) * (size_t)(L_ * L_);
    int key = i * 2 + br;
    switch (key) {
        case 0: expand_body<3, 0>(sAcc, outp); break;
        case 1: expand_body<3, 1>(sAcc, outp); break;
        case 2: expand_body<5, 0>(sAcc, outp); break;
        case 3: expand_body<5, 1>(sAcc, outp); break;
        case 4: expand_body<7, 0>(sAcc, outp); break;
        case 5: expand_body<7, 1>(sAcc, outp); break;
    }
}

extern "C" void kernel_launch(void* const* d_in, const int* in_sizes, int n_in,
                              void* d_out, int out_size, void* d_ws, size_t ws_size,
                              hipStream_t stream) {
    const float* x   = (const float*)d_in[0];
    const float* cp0 = (const float*)d_in[1];
    const float* cn0 = (const float*)d_in[2];
    const float* cp1 = (const float*)d_in[3];
    const float* cn1 = (const float*)d_in[4];
    const float* cp2 = (const float*)d_in[5];
    const float* cn2 = (const float*)d_in[6];
    const float* Wq  = (const float*)d_in[7];
    const float* bq  = (const float*)d_in[8];
    const float* Wk  = (const float*)d_in[9];
    const float* bk  = (const float*)d_in[10];
    float* ws = (float*)d_ws;
    float* out = (float*)d_out;

    const int use_partial = (ws_size >= WS_NEED_BYTES) ? 1 : 0;

    hipLaunchKernelGGL(prep_kernel, dim3(PREP_BLOCKS), dim3(256), 0, stream, x, ws);
    if (use_partial) {
        hipLaunchKernelGGL(lr2_kernel, dim3(NCOMBO, 14, 4), dim3(256), 0, stream,
                           cp0, cn0, cp1, cn1, cp2, cn2, Wq, bq, Wk, bk, ws);
    } else {
        hipLaunchKernelGGL(lr_kernel, dim3(NCOMBO, 27), dim3(256), 0, stream,
                           cp0, cn0, cp1, cn1, cp2, cn2, Wq, bq, Wk, bk, ws);
    }
    hipLaunchKernelGGL(mm_kernel, dim3(NCOMBO, 49), dim3(256), 0, stream, ws, use_partial);
    if (!use_partial) {
        hipLaunchKernelGGL(pack_kernel, dim3(NCOMBO, 16), dim3(256), 0, stream, ws);
        hipLaunchKernelGGL(zero_acc, dim3(Z_BLOCKS), dim3(256), 0, stream, ws);
    }

    // 3 attn dispatches: pair<3> (LDS union free), <5,0> alone (would cost
    // partners 2 blocks/CU), triple {<7,0>,<7,1>,<5,1>} (union 21.5KB, all
    // stay at 7 blocks/CU).
    hipLaunchKernelGGL((attn_pair<3>), dim3(B_, 3, 33), dim3(256), 0, stream, ws, ws);
    hipLaunchKernelGGL((attn2<5, 0>),  dim3(B_, 3, 14), dim3(256), 0, stream, ws, ws);
    hipLaunchKernelGGL(attn_triple,    dim3(B_, 3, 28), dim3(256), 0, stream, ws, ws);

    hipLaunchKernelGGL(expand_kernel, dim3(NCOMBO, B_), dim3(256), 0, stream, ws, out);
}